// Round 1
// baseline (1785.218 us; speedup 1.0000x reference)
//
#include <hip/hip_runtime.h>
#include <cmath>

#define DMODEL 768
#define SEQ    1024
#define NHEAD  12
#define HDIM   64
#define MTOT   16384   // 16 * 1024

// ---------------------------------------------------------------------------
// RoPE cos/sin tables: tab[0]=cos_x, tab[1]=sin_x, tab[2]=cos_y, tab[3]=sin_y
// each [1024][16] fp32, computed in fp64 to match np fp32 reference closely.
// ---------------------------------------------------------------------------
__global__ __launch_bounds__(256)
void rope_table_kernel(float* __restrict__ tab) {
  int idx = blockIdx.x * 256 + threadIdx.x;   // l*16 + p
  if (idx >= SEQ * 16) return;
  int l = idx >> 4, p = idx & 15;
  double u = ((double)(l & 31) + 0.5) / 32.0;   // x coord: l % 32
  double v = ((double)(l >> 5) + 0.5) / 32.0;   // y coord: l / 32
  double freq = (double)p / (15.0 + 1e-9);
  double inv = pow(10000.0, -freq);
  tab[idx]         = (float)cos(u * inv);
  tab[16384 + idx] = (float)sin(u * inv);
  tab[32768 + idx] = (float)cos(v * inv);
  tab[49152 + idx] = (float)sin(v * inv);
}

// ---------------------------------------------------------------------------
// C[M,768] = A[M,768] @ B[768,768] + bias[768], optional fused RoPE epilogue.
// 64x64 tile / block, 256 threads, 4x4 accum per thread, BK=16, fp32.
// ---------------------------------------------------------------------------
__global__ __launch_bounds__(256)
void gemm_bias_rope_kernel(const float* __restrict__ A, const float* __restrict__ B,
                           const float* __restrict__ bias, float* __restrict__ C,
                           const float* __restrict__ rope, int applyRope) {
  __shared__ __align__(16) float As[64][20];
  __shared__ __align__(16) float Bs[16][68];
  const int t  = threadIdx.x;
  const int tx = t & 15, ty = t >> 4;
  const int m0 = blockIdx.x * 64;
  const int n0 = blockIdx.y * 64;
  const int arow = t >> 2,  ac = (t & 3)  * 4;
  const int brow = t >> 4,  bc = (t & 15) * 4;

  float acc[4][4] = {};

  for (int k0 = 0; k0 < DMODEL; k0 += 16) {
    __syncthreads();
    *(float4*)&As[arow][ac] = *(const float4*)&A[(size_t)(m0 + arow) * DMODEL + k0 + ac];
    *(float4*)&Bs[brow][bc] = *(const float4*)&B[(size_t)(k0 + brow) * DMODEL + n0 + bc];
    __syncthreads();
#pragma unroll
    for (int kk = 0; kk < 16; ++kk) {
      const float4 b4 = *(const float4*)&Bs[kk][tx * 4];
      const float a0 = As[ty * 4 + 0][kk];
      const float a1 = As[ty * 4 + 1][kk];
      const float a2 = As[ty * 4 + 2][kk];
      const float a3 = As[ty * 4 + 3][kk];
      acc[0][0] += a0 * b4.x; acc[0][1] += a0 * b4.y; acc[0][2] += a0 * b4.z; acc[0][3] += a0 * b4.w;
      acc[1][0] += a1 * b4.x; acc[1][1] += a1 * b4.y; acc[1][2] += a1 * b4.z; acc[1][3] += a1 * b4.w;
      acc[2][0] += a2 * b4.x; acc[2][1] += a2 * b4.y; acc[2][2] += a2 * b4.z; acc[2][3] += a2 * b4.w;
      acc[3][0] += a3 * b4.x; acc[3][1] += a3 * b4.y; acc[3][2] += a3 * b4.z; acc[3][3] += a3 * b4.w;
    }
  }

  const float4 bi = *(const float4*)&bias[n0 + tx * 4];
#pragma unroll
  for (int i = 0; i < 4; ++i) {
    acc[i][0] += bi.x; acc[i][1] += bi.y; acc[i][2] += bi.z; acc[i][3] += bi.w;
  }

  if (applyRope) {
    // cols n = n0 + tx*4 + j; head-dim dd = tx*4+j (n0 is a multiple of 64);
    // rope pair p = dd/2: p<16 -> (cos_x,sin_x), else (cos_y,sin_y).
#pragma unroll
    for (int i = 0; i < 4; ++i) {
      const int l = (m0 + ty * 4 + i) & (SEQ - 1);
#pragma unroll
      for (int pr = 0; pr < 2; ++pr) {
        const int p  = tx * 2 + pr;
        const int tb = (p < 16) ? 0 : 32768;
        const int pi = (p < 16) ? p : p - 16;
        const float cs = rope[tb + l * 16 + pi];
        const float sn = rope[tb + 16384 + l * 16 + pi];
        const float x = acc[i][pr * 2 + 0], y = acc[i][pr * 2 + 1];
        acc[i][pr * 2 + 0] = x * cs - y * sn;
        acc[i][pr * 2 + 1] = x * sn + y * cs;
      }
    }
  }

#pragma unroll
  for (int i = 0; i < 4; ++i) {
    float4 o;
    o.x = acc[i][0]; o.y = acc[i][1]; o.z = acc[i][2]; o.w = acc[i][3];
    *(float4*)&C[(size_t)(m0 + ty * 4 + i) * DMODEL + n0 + tx * 4] = o;
  }
}

// ---------------------------------------------------------------------------
// Flash-style fp32 attention. Block = 256 thr handles one 64-row q-tile of one
// (n, h). Iterates 16 k-tiles of 64 rows; online softmax; K and V share LDS.
// q/k/v layout: [n][l][h*64+d] (row stride 768).
// ---------------------------------------------------------------------------
__global__ __launch_bounds__(256)
void attn_kernel(const float* __restrict__ qb, const float* __restrict__ kb,
                 const float* __restrict__ vb, float* __restrict__ ob) {
  __shared__ __align__(16) float Qs[64][68];
  __shared__ __align__(16) float Ks[64][68];
  __shared__ __align__(16) float Ps[64][68];
  const int t = threadIdx.x, tx = t & 15, ty = t >> 4;
  const int qt = blockIdx.x;
  const size_t headoff = (size_t)blockIdx.z * SEQ * DMODEL + (size_t)blockIdx.y * HDIM;

#pragma unroll
  for (int s = 0; s < 4; ++s) {
    const int idx = t + 256 * s;
    const int row = idx >> 4, c = (idx & 15) * 4;
    *(float4*)&Qs[row][c] = *(const float4*)&qb[headoff + (size_t)(qt * 64 + row) * DMODEL + c];
  }

  float O[4][4] = {};
  float mrun[4] = {-1e30f, -1e30f, -1e30f, -1e30f};
  float lrun[4] = {0.f, 0.f, 0.f, 0.f};

  for (int kt = 0; kt < 16; ++kt) {
    __syncthreads();   // everyone done reading Ks (as V) from previous iter
#pragma unroll
    for (int s = 0; s < 4; ++s) {
      const int idx = t + 256 * s;
      const int row = idx >> 4, c = (idx & 15) * 4;
      *(float4*)&Ks[row][c] = *(const float4*)&kb[headoff + (size_t)(kt * 64 + row) * DMODEL + c];
    }
    __syncthreads();

    // S = Q @ K^T for this tile; thread covers rows ty*4+i, cols tx+16*j
    float sc4[4][4] = {};
#pragma unroll
    for (int d4 = 0; d4 < 16; ++d4) {
      float4 qv[4], kv[4];
#pragma unroll
      for (int i = 0; i < 4; ++i) qv[i] = *(const float4*)&Qs[ty * 4 + i][d4 * 4];
#pragma unroll
      for (int j = 0; j < 4; ++j) kv[j] = *(const float4*)&Ks[tx + 16 * j][d4 * 4];
#pragma unroll
      for (int i = 0; i < 4; ++i)
#pragma unroll
        for (int j = 0; j < 4; ++j)
          sc4[i][j] += qv[i].x * kv[j].x + qv[i].y * kv[j].y +
                       qv[i].z * kv[j].z + qv[i].w * kv[j].w;
    }

    // online softmax per q-row (16 threads per row share via shfl width 16)
#pragma unroll
    for (int i = 0; i < 4; ++i) {
#pragma unroll
      for (int j = 0; j < 4; ++j) sc4[i][j] *= 0.125f;
      float tm = fmaxf(fmaxf(sc4[i][0], sc4[i][1]), fmaxf(sc4[i][2], sc4[i][3]));
      for (int off = 1; off < 16; off <<= 1) tm = fmaxf(tm, __shfl_xor(tm, off, 16));
      const float nm  = fmaxf(mrun[i], tm);
      const float scl = expf(mrun[i] - nm);
      mrun[i] = nm;
      float rs = 0.f;
#pragma unroll
      for (int j = 0; j < 4; ++j) { const float p = expf(sc4[i][j] - nm); sc4[i][j] = p; rs += p; }
      for (int off = 1; off < 16; off <<= 1) rs += __shfl_xor(rs, off, 16);
      lrun[i] = lrun[i] * scl + rs;
#pragma unroll
      for (int j = 0; j < 4; ++j) O[i][j] *= scl;
#pragma unroll
      for (int j = 0; j < 4; ++j) Ps[ty * 4 + i][tx + 16 * j] = sc4[i][j];
    }
    __syncthreads();   // Ps visible; all done reading Ks as K

    // load V tile into Ks
#pragma unroll
    for (int s = 0; s < 4; ++s) {
      const int idx = t + 256 * s;
      const int row = idx >> 4, c = (idx & 15) * 4;
      *(float4*)&Ks[row][c] = *(const float4*)&vb[headoff + (size_t)(kt * 64 + row) * DMODEL + c];
    }
    __syncthreads();

    // O += P @ V ; thread covers rows ty*4+i, dims tx*4+j
#pragma unroll 8
    for (int k = 0; k < 64; ++k) {
      const float4 vv = *(const float4*)&Ks[k][tx * 4];
      const float p0 = Ps[ty * 4 + 0][k];
      const float p1 = Ps[ty * 4 + 1][k];
      const float p2 = Ps[ty * 4 + 2][k];
      const float p3 = Ps[ty * 4 + 3][k];
      O[0][0] += p0 * vv.x; O[0][1] += p0 * vv.y; O[0][2] += p0 * vv.z; O[0][3] += p0 * vv.w;
      O[1][0] += p1 * vv.x; O[1][1] += p1 * vv.y; O[1][2] += p1 * vv.z; O[1][3] += p1 * vv.w;
      O[2][0] += p2 * vv.x; O[2][1] += p2 * vv.y; O[2][2] += p2 * vv.z; O[2][3] += p2 * vv.w;
      O[3][0] += p3 * vv.x; O[3][1] += p3 * vv.y; O[3][2] += p3 * vv.z; O[3][3] += p3 * vv.w;
    }
  }

#pragma unroll
  for (int i = 0; i < 4; ++i) {
    const float inv = 1.0f / lrun[i];
    float4 o;
    o.x = O[i][0] * inv; o.y = O[i][1] * inv; o.z = O[i][2] * inv; o.w = O[i][3] * inv;
    *(float4*)&ob[headoff + (size_t)(qt * 64 + ty * 4 + i) * DMODEL + tx * 4] = o;
  }
}

// ---------------------------------------------------------------------------
extern "C" void kernel_launch(void* const* d_in, const int* in_sizes, int n_in,
                              void* d_out, int out_size, void* d_ws, size_t ws_size,
                              hipStream_t stream) {
  const float* Xq  = (const float*)d_in[0];
  const float* Xkv = (const float*)d_in[1];
  const float* Wq  = (const float*)d_in[2];
  const float* bq  = (const float*)d_in[3];
  const float* Wk  = (const float*)d_in[4];
  const float* bk  = (const float*)d_in[5];
  const float* Wv  = (const float*)d_in[6];
  const float* bv  = (const float*)d_in[7];
  const float* Wo  = (const float*)d_in[8];
  const float* bo  = (const float*)d_in[9];
  float* out = (float*)d_out;
  float* ws  = (float*)d_ws;

  const size_t ropeF = 4 * SEQ * 16;            // 65536 floats
  const size_t bufF  = (size_t)MTOT * DMODEL;   // 12582912 floats
  if (ws_size < (ropeF + 4 * bufF) * sizeof(float)) return;  // need ~202 MB

  float* rope = ws;
  float* qb = ws + ropeF;
  float* kb = qb + bufF;
  float* vb = kb + bufF;
  float* ab = vb + bufF;

  rope_table_kernel<<<64, 256, 0, stream>>>(rope);

  dim3 gg(MTOT / 64, DMODEL / 64, 1);
  gemm_bias_rope_kernel<<<gg, 256, 0, stream>>>(Xq,  Wq, bq, qb, rope, 1);
  gemm_bias_rope_kernel<<<gg, 256, 0, stream>>>(Xkv, Wk, bk, kb, rope, 1);
  gemm_bias_rope_kernel<<<gg, 256, 0, stream>>>(Xkv, Wv, bv, vb, rope, 0);

  attn_kernel<<<dim3(SEQ / 64, NHEAD, 16), 256, 0, stream>>>(qb, kb, vb, ab);

  gemm_bias_rope_kernel<<<gg, 256, 0, stream>>>(ab, Wo, bo, out, rope, 0);
}

// Round 2
// 1317.743 us; speedup vs baseline: 1.3548x; 1.3548x over previous
//
#include <hip/hip_runtime.h>
#include <cmath>

#define DMODEL 768
#define SEQ    1024
#define NH     12
#define HDIM   64
#define MTOT   16384   // 16 * 1024

typedef __attribute__((ext_vector_type(8))) short short8v;
typedef __attribute__((ext_vector_type(4))) float f32x4;

// round-to-nearest-even fp32 -> bf16 (as ushort bit pattern)
__device__ __forceinline__ unsigned short bf16rn(float x) {
  unsigned u = __float_as_uint(x);
  return (unsigned short)((u + 0x7FFFu + ((u >> 16) & 1u)) >> 16);
}
// split x ~= hi + lo, both bf16 (RN); residual error ~2^-18 |x|
__device__ __forceinline__ void bsplit(float x, unsigned short& h, unsigned short& l) {
  h = bf16rn(x);
  float hf = __uint_as_float((unsigned)h << 16);
  l = bf16rn(x - hf);
}

// ---------------------------------------------------------------------------
// RoPE cos/sin tables, fp64-accurate
// ---------------------------------------------------------------------------
__global__ __launch_bounds__(256)
void rope_table_kernel(float* __restrict__ tab) {
  int idx = blockIdx.x * 256 + threadIdx.x;   // l*16 + p
  if (idx >= SEQ * 16) return;
  int l = idx >> 4, p = idx & 15;
  double u = ((double)(l & 31) + 0.5) / 32.0;
  double v = ((double)(l >> 5) + 0.5) / 32.0;
  double freq = (double)p / (15.0 + 1e-9);
  double inv = pow(10000.0, -freq);
  tab[idx]         = (float)cos(u * inv);
  tab[16384 + idx] = (float)sin(u * inv);
  tab[32768 + idx] = (float)cos(v * inv);
  tab[49152 + idx] = (float)sin(v * inv);
}

// ---------------------------------------------------------------------------
// fp32 GEMM  C[M,768] = A[M,768] @ B[768,768] + bias.
// mode 0: write fp32 C.  mode 1: apply RoPE, split to bf16 hi/lo, write
// per-head layout [n][h][l][64] (head == 64-col tile since N-tile = 64).
// ---------------------------------------------------------------------------
__global__ __launch_bounds__(256)
void gemm_kernel(const float* __restrict__ A, const float* __restrict__ B,
                 const float* __restrict__ bias, float* __restrict__ C,
                 unsigned short* __restrict__ Hi, unsigned short* __restrict__ Lo,
                 const float* __restrict__ rope, int mode) {
  __shared__ __align__(16) float As[64][20];
  __shared__ __align__(16) float Bs[16][68];
  const int t  = threadIdx.x;
  const int tx = t & 15, ty = t >> 4;
  const int m0 = blockIdx.x * 64;
  const int n0 = blockIdx.y * 64;
  const int arow = t >> 2,  ac = (t & 3)  * 4;
  const int brow = t >> 4,  bc = (t & 15) * 4;

  float acc[4][4] = {};

  for (int k0 = 0; k0 < DMODEL; k0 += 16) {
    __syncthreads();
    *(float4*)&As[arow][ac] = *(const float4*)&A[(size_t)(m0 + arow) * DMODEL + k0 + ac];
    *(float4*)&Bs[brow][bc] = *(const float4*)&B[(size_t)(k0 + brow) * DMODEL + n0 + bc];
    __syncthreads();
#pragma unroll
    for (int kk = 0; kk < 16; ++kk) {
      const float4 b4 = *(const float4*)&Bs[kk][tx * 4];
      const float a0 = As[ty * 4 + 0][kk];
      const float a1 = As[ty * 4 + 1][kk];
      const float a2 = As[ty * 4 + 2][kk];
      const float a3 = As[ty * 4 + 3][kk];
      acc[0][0] += a0 * b4.x; acc[0][1] += a0 * b4.y; acc[0][2] += a0 * b4.z; acc[0][3] += a0 * b4.w;
      acc[1][0] += a1 * b4.x; acc[1][1] += a1 * b4.y; acc[1][2] += a1 * b4.z; acc[1][3] += a1 * b4.w;
      acc[2][0] += a2 * b4.x; acc[2][1] += a2 * b4.y; acc[2][2] += a2 * b4.z; acc[2][3] += a2 * b4.w;
      acc[3][0] += a3 * b4.x; acc[3][1] += a3 * b4.y; acc[3][2] += a3 * b4.z; acc[3][3] += a3 * b4.w;
    }
  }

  const float4 bi = *(const float4*)&bias[n0 + tx * 4];
#pragma unroll
  for (int i = 0; i < 4; ++i) {
    acc[i][0] += bi.x; acc[i][1] += bi.y; acc[i][2] += bi.z; acc[i][3] += bi.w;
  }

  if (mode == 1) {
    const int h = blockIdx.y;   // N-tile == head
#pragma unroll
    for (int i = 0; i < 4; ++i) {
      const int m = m0 + ty * 4 + i;
      const int l = m & (SEQ - 1);
      const int nb = m >> 10;
#pragma unroll
      for (int pr = 0; pr < 2; ++pr) {
        const int p  = tx * 2 + pr;
        const int tb = (p < 16) ? 0 : 32768;
        const int pi = (p < 16) ? p : p - 16;
        const float cs = rope[tb + l * 16 + pi];
        const float sn = rope[tb + 16384 + l * 16 + pi];
        const float x = acc[i][pr * 2 + 0], y = acc[i][pr * 2 + 1];
        acc[i][pr * 2 + 0] = x * cs - y * sn;
        acc[i][pr * 2 + 1] = x * sn + y * cs;
      }
      ushort4 hv, lv;
      bsplit(acc[i][0], hv.x, lv.x);
      bsplit(acc[i][1], hv.y, lv.y);
      bsplit(acc[i][2], hv.z, lv.z);
      bsplit(acc[i][3], hv.w, lv.w);
      const size_t off = (((size_t)nb * NH + h) * SEQ + l) * HDIM + tx * 4;
      *(ushort4*)&Hi[off] = hv;
      *(ushort4*)&Lo[off] = lv;
    }
  } else {
#pragma unroll
    for (int i = 0; i < 4; ++i) {
      float4 o;
      o.x = acc[i][0]; o.y = acc[i][1]; o.z = acc[i][2]; o.w = acc[i][3];
      *(float4*)&C[(size_t)(m0 + ty * 4 + i) * DMODEL + n0 + tx * 4] = o;
    }
  }
}

// ---------------------------------------------------------------------------
// V transpose + split: vb [n][l][768] fp32 -> vt hi/lo [n][h][d][1024] bf16
// ---------------------------------------------------------------------------
__global__ __launch_bounds__(256)
void v_transpose_kernel(const float* __restrict__ vb,
                        unsigned short* __restrict__ vth, unsigned short* __restrict__ vtl) {
  __shared__ float Vs[64][68];
  const int t = threadIdx.x;
  const int lt = blockIdx.x, h = blockIdx.y, n = blockIdx.z;
  {
    const int lr = t >> 2, db = (t & 3) * 16;
    const float* src = vb + ((size_t)n * SEQ + lt * 64 + lr) * DMODEL + h * HDIM + db;
#pragma unroll
    for (int c = 0; c < 16; c += 4)
      *(float4*)&Vs[lr][db + c] = *(const float4*)&src[c];
  }
  __syncthreads();
  const int d = t >> 2, lb = (t & 3) * 16;
  short8v hi0, hi1, lo0, lo1;
#pragma unroll
  for (int i = 0; i < 8; ++i) {
    unsigned short hh, ll;
    bsplit(Vs[lb + i][d], hh, ll);
    hi0[i] = (short)hh; lo0[i] = (short)ll;
  }
#pragma unroll
  for (int i = 0; i < 8; ++i) {
    unsigned short hh, ll;
    bsplit(Vs[lb + 8 + i][d], hh, ll);
    hi1[i] = (short)hh; lo1[i] = (short)ll;
  }
  const size_t off = (((size_t)n * NH + h) * HDIM + d) * SEQ + lt * 64 + lb;
  *(short8v*)&vth[off]     = hi0;
  *(short8v*)&vth[off + 8] = hi1;
  *(short8v*)&vtl[off]     = lo0;
  *(short8v*)&vtl[off + 8] = lo1;
}

// ---------------------------------------------------------------------------
// Flash attention, split-bf16 MFMA (16x16x32). Block = 256 thr = 4 waves,
// one 64-row q-tile of one (n,h). Wave w owns q-rows w*16..w*16+15.
// ---------------------------------------------------------------------------
__global__ __launch_bounds__(256)
void attn_mfma_kernel(const unsigned short* __restrict__ qh, const unsigned short* __restrict__ ql,
                      const unsigned short* __restrict__ kh, const unsigned short* __restrict__ kl,
                      const unsigned short* __restrict__ vth, const unsigned short* __restrict__ vtl,
                      float* __restrict__ ob) {
  __shared__ unsigned short Bh[64][72];   // K tile [key][d] then V^T tile [d][key]
  __shared__ unsigned short Bl[64][72];
  __shared__ float Ps[64][68];            // P tile [qrow][key], f32

  const int t = threadIdx.x;
  const int lane = t & 63, w = t >> 6;
  const int l15 = lane & 15, l4 = lane >> 4;

  // XCD-locality swizzle: all 16 q-tiles of one head on one XCD
  const int bid = blockIdx.x;
  const int xcd = bid & 7;
  const int rest = bid >> 3;
  const int qt = rest & 15;
  const int hl = (rest >> 4) * 8 + xcd;   // 0..191
  const int h = hl % NH, n = hl / NH;

  const size_t qkbase = ((size_t)n * NH + h) * SEQ * HDIM;   // [l][64]
  const size_t vtbase = ((size_t)n * NH + h) * HDIM * SEQ;   // [d][1024]

  // Q fragments in registers: A row = l15 (within wave's 16 rows), k contiguous
  short8v qfh[2], qfl[2];
  {
    const size_t qoff = qkbase + (size_t)(qt * 64 + w * 16 + l15) * HDIM + l4 * 8;
    qfh[0] = *(const short8v*)&qh[qoff];
    qfh[1] = *(const short8v*)&qh[qoff + 32];
    qfl[0] = *(const short8v*)&ql[qoff];
    qfl[1] = *(const short8v*)&ql[qoff + 32];
  }

  f32x4 Oa[4] = {};   // j: d cols 16j + l15; element r: row w*16 + l4*4 + r
  float mrun[4] = {-INFINITY, -INFINITY, -INFINITY, -INFINITY};
  float lrun[4] = {0.f, 0.f, 0.f, 0.f};

  const int sr = t >> 2, sc = (t & 3) * 16;   // staging: row, col-block

  for (int kt = 0; kt < 16; ++kt) {
    __syncthreads();   // everyone done with prev V reads
    {
      const size_t g = qkbase + (size_t)(kt * 64 + sr) * HDIM + sc;
      *(short8v*)&Bh[sr][sc]     = *(const short8v*)&kh[g];
      *(short8v*)&Bh[sr][sc + 8] = *(const short8v*)&kh[g + 8];
      *(short8v*)&Bl[sr][sc]     = *(const short8v*)&kl[g];
      *(short8v*)&Bl[sr][sc + 8] = *(const short8v*)&kl[g + 8];
    }
    __syncthreads();

    // S = Q K^T (3-term split)
    f32x4 S[4] = {};
#pragma unroll
    for (int ks = 0; ks < 2; ++ks) {
#pragma unroll
      for (int j = 0; j < 4; ++j) {
        const short8v bh = *(const short8v*)&Bh[l15 + 16 * j][ks * 32 + l4 * 8];
        const short8v bl = *(const short8v*)&Bl[l15 + 16 * j][ks * 32 + l4 * 8];
        S[j] = __builtin_amdgcn_mfma_f32_16x16x32_bf16(qfh[ks], bh, S[j], 0, 0, 0);
        S[j] = __builtin_amdgcn_mfma_f32_16x16x32_bf16(qfl[ks], bh, S[j], 0, 0, 0);
        S[j] = __builtin_amdgcn_mfma_f32_16x16x32_bf16(qfh[ks], bl, S[j], 0, 0, 0);
      }
    }

    // online softmax; rows = w*16 + l4*4 + r, cols = l15 + 16j
#pragma unroll
    for (int r = 0; r < 4; ++r) {
      float s0 = S[0][r] * 0.125f, s1 = S[1][r] * 0.125f;
      float s2 = S[2][r] * 0.125f, s3 = S[3][r] * 0.125f;
      float tm = fmaxf(fmaxf(s0, s1), fmaxf(s2, s3));
      for (int off = 1; off < 16; off <<= 1) tm = fmaxf(tm, __shfl_xor(tm, off, 16));
      const float nm  = fmaxf(mrun[r], tm);
      const float scl = expf(mrun[r] - nm);
      const float p0 = expf(s0 - nm), p1 = expf(s1 - nm);
      const float p2 = expf(s2 - nm), p3 = expf(s3 - nm);
      float rs = p0 + p1 + p2 + p3;
      for (int off = 1; off < 16; off <<= 1) rs += __shfl_xor(rs, off, 16);
      mrun[r] = nm;
      lrun[r] = lrun[r] * scl + rs;
      Oa[0][r] *= scl; Oa[1][r] *= scl; Oa[2][r] *= scl; Oa[3][r] *= scl;
      const int prow = w * 16 + l4 * 4 + r;
      Ps[prow][l15]      = p0;
      Ps[prow][l15 + 16] = p1;
      Ps[prow][l15 + 32] = p2;
      Ps[prow][l15 + 48] = p3;
    }

    __syncthreads();   // all waves done reading K from Bh/Bl
    {
      const size_t g = vtbase + (size_t)sr * SEQ + kt * 64 + sc;
      *(short8v*)&Bh[sr][sc]     = *(const short8v*)&vth[g];
      *(short8v*)&Bh[sr][sc + 8] = *(const short8v*)&vth[g + 8];
      *(short8v*)&Bl[sr][sc]     = *(const short8v*)&vtl[g];
      *(short8v*)&Bl[sr][sc + 8] = *(const short8v*)&vtl[g + 8];
    }
    __syncthreads();

    // O += P V (3-term split). P a-frag: row=l15, key contiguous (own wave rows)
#pragma unroll
    for (int ks = 0; ks < 2; ++ks) {
      float pf[8];
      *(f32x4*)&pf[0] = *(const f32x4*)&Ps[w * 16 + l15][ks * 32 + l4 * 8];
      *(f32x4*)&pf[4] = *(const f32x4*)&Ps[w * 16 + l15][ks * 32 + l4 * 8 + 4];
      short8v ph, pl;
#pragma unroll
      for (int e = 0; e < 8; ++e) {
        unsigned short hh, ll;
        bsplit(pf[e], hh, ll);
        ph[e] = (short)hh; pl[e] = (short)ll;
      }
#pragma unroll
      for (int j = 0; j < 4; ++j) {
        const short8v vh = *(const short8v*)&Bh[l15 + 16 * j][ks * 32 + l4 * 8];
        const short8v vl = *(const short8v*)&Bl[l15 + 16 * j][ks * 32 + l4 * 8];
        Oa[j] = __builtin_amdgcn_mfma_f32_16x16x32_bf16(ph, vh, Oa[j], 0, 0, 0);
        Oa[j] = __builtin_amdgcn_mfma_f32_16x16x32_bf16(pl, vh, Oa[j], 0, 0, 0);
        Oa[j] = __builtin_amdgcn_mfma_f32_16x16x32_bf16(ph, vl, Oa[j], 0, 0, 0);
      }
    }
  }

  // epilogue: O /= l, write fp32 [n][l][768]
#pragma unroll
  for (int r = 0; r < 4; ++r) {
    const float inv = 1.0f / lrun[r];
    const size_t row = (size_t)n * SEQ + qt * 64 + w * 16 + l4 * 4 + r;
#pragma unroll
    for (int j = 0; j < 4; ++j)
      ob[row * DMODEL + h * HDIM + 16 * j + l15] = Oa[j][r] * inv;
  }
}

// ---------------------------------------------------------------------------
extern "C" void kernel_launch(void* const* d_in, const int* in_sizes, int n_in,
                              void* d_out, int out_size, void* d_ws, size_t ws_size,
                              hipStream_t stream) {
  (void)in_sizes; (void)n_in; (void)out_size;
  const float* Xq  = (const float*)d_in[0];
  const float* Xkv = (const float*)d_in[1];
  const float* Wq  = (const float*)d_in[2];
  const float* bq  = (const float*)d_in[3];
  const float* Wk  = (const float*)d_in[4];
  const float* bk  = (const float*)d_in[5];
  const float* Wv  = (const float*)d_in[6];
  const float* bv  = (const float*)d_in[7];
  const float* Wo  = (const float*)d_in[8];
  const float* bo  = (const float*)d_in[9];
  float* out = (float*)d_out;

  if (ws_size < 201588736ull) return;
  char* W = (char*)d_ws;
  float* rope = (float*)W;                                    // 262,144 B
  unsigned short* qhi = (unsigned short*)(W + 262144);
  unsigned short* qlo = qhi + 12582912;
  unsigned short* khi = qlo + 12582912;
  unsigned short* klo = khi + 12582912;
  unsigned short* vth = klo + 12582912;
  unsigned short* vtl = vth + 12582912;
  float* vb = (float*)(W + 262144 + 6ull * 25165824);         // fp32 V
  float* ab = vb;                                             // attn out aliases vb

  rope_table_kernel<<<64, 256, 0, stream>>>(rope);

  dim3 gg(MTOT / 64, DMODEL / 64, 1);
  gemm_kernel<<<gg, 256, 0, stream>>>(Xq,  Wq, bq, nullptr, qhi, qlo, rope, 1);
  gemm_kernel<<<gg, 256, 0, stream>>>(Xkv, Wk, bk, nullptr, khi, klo, rope, 1);
  gemm_kernel<<<gg, 256, 0, stream>>>(Xkv, Wv, bv, vb, nullptr, nullptr, rope, 0);

  v_transpose_kernel<<<dim3(16, NH, 16), 256, 0, stream>>>(vb, vth, vtl);

  attn_mfma_kernel<<<3072, 256, 0, stream>>>(qhi, qlo, khi, klo, vth, vtl, ab);

  gemm_kernel<<<gg, 256, 0, stream>>>(ab, Wo, bo, out, nullptr, nullptr, rope, 0);
}

// Round 3
// 648.740 us; speedup vs baseline: 2.7518x; 2.0312x over previous
//
#include <hip/hip_runtime.h>
#include <cmath>

#define DMODEL 768
#define SEQ    1024
#define NH     12
#define HDIM   64
#define MTOT   16384   // 16 * 1024

typedef unsigned short ushort_t;
typedef __attribute__((ext_vector_type(8))) short short8v;
typedef __attribute__((ext_vector_type(4))) float f32x4;

// round-to-nearest-even fp32 -> bf16 bits
__device__ __forceinline__ ushort_t bf16rn(float x) {
  unsigned u = __float_as_uint(x);
  return (ushort_t)((u + 0x7FFFu + ((u >> 16) & 1u)) >> 16);
}
__device__ __forceinline__ void bsplit(float x, ushort_t& h, ushort_t& l) {
  h = bf16rn(x);
  float hf = __uint_as_float((unsigned)h << 16);
  l = bf16rn(x - hf);
}

// async global -> LDS, 16 bytes per lane
__device__ __forceinline__ void gld16(const void* g, void* l) {
  __builtin_amdgcn_global_load_lds(
      (const __attribute__((address_space(1))) int*)g,
      (__attribute__((address_space(3))) int*)l, 16, 0, 0);
}

// ---------------------------------------------------------------------------
// RoPE tables (fp64-accurate): [cos_x | sin_x | cos_y | sin_y], each [1024][16]
// ---------------------------------------------------------------------------
__global__ __launch_bounds__(256)
void rope_table_kernel(float* __restrict__ tab) {
  int idx = blockIdx.x * 256 + threadIdx.x;
  if (idx >= SEQ * 16) return;
  int l = idx >> 4, p = idx & 15;
  double u = ((double)(l & 31) + 0.5) / 32.0;
  double v = ((double)(l >> 5) + 0.5) / 32.0;
  double freq = (double)p / (15.0 + 1e-9);
  double inv = pow(10000.0, -freq);
  tab[idx]         = (float)cos(u * inv);
  tab[16384 + idx] = (float)sin(u * inv);
  tab[32768 + idx] = (float)cos(v * inv);
  tab[49152 + idx] = (float)sin(v * inv);
}

// ---------------------------------------------------------------------------
// fp32 -> split bf16 hi/lo, 8 elems/thread
// ---------------------------------------------------------------------------
__global__ __launch_bounds__(256)
void split_x_kernel(const float* __restrict__ X, ushort_t* __restrict__ H,
                    ushort_t* __restrict__ L) {
  const int i = blockIdx.x * 256 + threadIdx.x;   // count fixed: 12582912/8
  const float4 a = ((const float4*)X)[i * 2];
  const float4 b = ((const float4*)X)[i * 2 + 1];
  short8v h, l;
  ushort_t hh, ll;
  bsplit(a.x, hh, ll); h[0] = (short)hh; l[0] = (short)ll;
  bsplit(a.y, hh, ll); h[1] = (short)hh; l[1] = (short)ll;
  bsplit(a.z, hh, ll); h[2] = (short)hh; l[2] = (short)ll;
  bsplit(a.w, hh, ll); h[3] = (short)hh; l[3] = (short)ll;
  bsplit(b.x, hh, ll); h[4] = (short)hh; l[4] = (short)ll;
  bsplit(b.y, hh, ll); h[5] = (short)hh; l[5] = (short)ll;
  bsplit(b.z, hh, ll); h[6] = (short)hh; l[6] = (short)ll;
  bsplit(b.w, hh, ll); h[7] = (short)hh; l[7] = (short)ll;
  ((short8v*)H)[i] = h;
  ((short8v*)L)[i] = l;
}

// ---------------------------------------------------------------------------
// W [768k][768n] fp32 -> Wt hi/lo bf16 [768n][768k] (transpose + split)
// ---------------------------------------------------------------------------
__global__ __launch_bounds__(256)
void wsplit_t_kernel(const float* __restrict__ W, ushort_t* __restrict__ TH,
                     ushort_t* __restrict__ TL) {
  __shared__ __align__(16) float T[64][65];
  const int t = threadIdx.x;
  const int kt = blockIdx.x, nt = blockIdx.y;
  const int r = t >> 2, c4 = (t & 3) * 16;
  const float* src = W + (size_t)(kt * 64 + r) * DMODEL + nt * 64 + c4;
#pragma unroll
  for (int i = 0; i < 16; i += 4)
    *(float4*)&T[r][c4 + i] = *(const float4*)&src[i];
  __syncthreads();
  short8v h0, h1, l0, l1;
#pragma unroll
  for (int i = 0; i < 8; ++i) {
    ushort_t hh, ll;
    bsplit(T[c4 + i][r], hh, ll);
    h0[i] = (short)hh; l0[i] = (short)ll;
  }
#pragma unroll
  for (int i = 0; i < 8; ++i) {
    ushort_t hh, ll;
    bsplit(T[c4 + 8 + i][r], hh, ll);
    h1[i] = (short)hh; l1[i] = (short)ll;
  }
  const size_t o = (size_t)(nt * 64 + r) * DMODEL + kt * 64 + c4;
  *(short8v*)&TH[o] = h0; *(short8v*)&TH[o + 8] = h1;
  *(short8v*)&TL[o] = l0; *(short8v*)&TL[o + 8] = l1;
}

// ---------------------------------------------------------------------------
// Split-bf16 MFMA GEMM: C[16384,768] = A @ B + bias (3-term hi/lo).
// A: [16384][768] hi/lo bf16. Bt: [768 n][768 k] hi/lo bf16 (pre-transposed).
// 128x128 tile, BK=32, 4 waves 2x2, 16x16x32 MFMA, global_load_lds staging.
// mode 0: fp32 C [M][768]. mode 1: +RoPE, split, per-head [n][h][l][64].
// mode 2: split, per-head (no rope).
// ---------------------------------------------------------------------------
__global__ __launch_bounds__(256)
void gemm_mfma_kernel(const ushort_t* __restrict__ Ahi, const ushort_t* __restrict__ Alo,
                      const ushort_t* __restrict__ Bhi, const ushort_t* __restrict__ Blo,
                      const float* __restrict__ bias, float* __restrict__ Cout,
                      ushort_t* __restrict__ Ohi, ushort_t* __restrict__ Olo,
                      const float* __restrict__ rope, int mode) {
  __shared__ __align__(16) ushort_t Ah[128][32];
  __shared__ __align__(16) ushort_t Al[128][32];
  __shared__ __align__(16) ushort_t Bh[128][32];
  __shared__ __align__(16) ushort_t Bl[128][32];

  const int t = threadIdx.x, lane = t & 63, w = t >> 6;
  const int l15 = lane & 15, l4 = lane >> 4;
  const int wm = w >> 1, wn = w & 1;
  const int m0 = blockIdx.x * 128, n0 = blockIdx.y * 128;

  // staging chunks: chunk c = t (rows 0..63) and c = t+256 (rows 64..127)
  const int crow = t >> 2, ccc = (t & 3) * 8;
  const ushort_t* pAh0 = Ahi + (size_t)(m0 + crow) * DMODEL + ccc;
  const ushort_t* pAh1 = pAh0 + (size_t)64 * DMODEL;
  const ushort_t* pAl0 = Alo + (size_t)(m0 + crow) * DMODEL + ccc;
  const ushort_t* pAl1 = pAl0 + (size_t)64 * DMODEL;
  const ushort_t* pBh0 = Bhi + (size_t)(n0 + crow) * DMODEL + ccc;
  const ushort_t* pBh1 = pBh0 + (size_t)64 * DMODEL;
  const ushort_t* pBl0 = Blo + (size_t)(n0 + crow) * DMODEL + ccc;
  const ushort_t* pBl1 = pBl0 + (size_t)64 * DMODEL;
  void* dAh0 = &Ah[crow][ccc];      void* dAh1 = &Ah[crow + 64][ccc];
  void* dAl0 = &Al[crow][ccc];      void* dAl1 = &Al[crow + 64][ccc];
  void* dBh0 = &Bh[crow][ccc];      void* dBh1 = &Bh[crow + 64][ccc];
  void* dBl0 = &Bl[crow][ccc];      void* dBl1 = &Bl[crow + 64][ccc];

  f32x4 acc[4][4] = {};

  for (int ks = 0; ks < DMODEL / 32; ++ks) {
    __syncthreads();
    gld16(pAh0, dAh0); gld16(pAh1, dAh1);
    gld16(pAl0, dAl0); gld16(pAl1, dAl1);
    gld16(pBh0, dBh0); gld16(pBh1, dBh1);
    gld16(pBl0, dBl0); gld16(pBl1, dBl1);
    pAh0 += 32; pAh1 += 32; pAl0 += 32; pAl1 += 32;
    pBh0 += 32; pBh1 += 32; pBl0 += 32; pBl1 += 32;
    __syncthreads();

    short8v afh[4], afl[4], bfh[4], bfl[4];
#pragma unroll
    for (int f = 0; f < 4; ++f) {
      afh[f] = *(const short8v*)&Ah[wm * 64 + f * 16 + l15][l4 * 8];
      afl[f] = *(const short8v*)&Al[wm * 64 + f * 16 + l15][l4 * 8];
      bfh[f] = *(const short8v*)&Bh[wn * 64 + f * 16 + l15][l4 * 8];
      bfl[f] = *(const short8v*)&Bl[wn * 64 + f * 16 + l15][l4 * 8];
    }
#pragma unroll
    for (int mf = 0; mf < 4; ++mf)
#pragma unroll
      for (int nf = 0; nf < 4; ++nf) {
        acc[mf][nf] = __builtin_amdgcn_mfma_f32_16x16x32_bf16(afh[mf], bfh[nf], acc[mf][nf], 0, 0, 0);
        acc[mf][nf] = __builtin_amdgcn_mfma_f32_16x16x32_bf16(afl[mf], bfh[nf], acc[mf][nf], 0, 0, 0);
        acc[mf][nf] = __builtin_amdgcn_mfma_f32_16x16x32_bf16(afh[mf], bfl[nf], acc[mf][nf], 0, 0, 0);
      }
  }

  float bcol[4];
#pragma unroll
  for (int nf = 0; nf < 4; ++nf) bcol[nf] = bias[n0 + wn * 64 + nf * 16 + l15];

  if (mode == 0) {
#pragma unroll
    for (int mf = 0; mf < 4; ++mf)
#pragma unroll
      for (int r = 0; r < 4; ++r) {
        const int m = m0 + wm * 64 + mf * 16 + l4 * 4 + r;
#pragma unroll
        for (int nf = 0; nf < 4; ++nf)
          Cout[(size_t)m * DMODEL + n0 + wn * 64 + nf * 16 + l15] = acc[mf][nf][r] + bcol[nf];
      }
  } else {
    const int h = blockIdx.y * 2 + wn;
#pragma unroll
    for (int mf = 0; mf < 4; ++mf)
#pragma unroll
      for (int r = 0; r < 4; ++r) {
        const int m = m0 + wm * 64 + mf * 16 + l4 * 4 + r;
        const int l = m & (SEQ - 1);
        const int nb = m >> 10;
        const size_t orow = ((size_t)(nb * NH + h) * SEQ + l) * HDIM;
#pragma unroll
        for (int nf = 0; nf < 4; ++nf) {
          float v = acc[mf][nf][r] + bcol[nf];
          if (mode == 1) {
            const float vp = __shfl_xor(v, 1, 64);
            const int tb = (nf < 2) ? 0 : 32768;
            const int pi = (nf & 1) * 8 + (l15 >> 1);
            const float c = rope[tb + l * 16 + pi];
            const float s = rope[tb + 16384 + l * 16 + pi];
            v = (l15 & 1) ? (vp * s + v * c) : (v * c - vp * s);
          }
          ushort_t hh, ll;
          bsplit(v, hh, ll);
          Ohi[orow + nf * 16 + l15] = hh;
          Olo[orow + nf * 16 + l15] = ll;
        }
      }
  }
}

// ---------------------------------------------------------------------------
// V transpose (bf16 hi/lo): [n][h][l][64] -> [n][h][d][1024]
// ---------------------------------------------------------------------------
__global__ __launch_bounds__(256)
void vtrans_kernel(const ushort_t* __restrict__ VH, const ushort_t* __restrict__ VL,
                   ushort_t* __restrict__ TH, ushort_t* __restrict__ TL) {
  __shared__ __align__(16) ushort_t Th[64][72];
  __shared__ __align__(16) ushort_t Tl[64][72];
  const int t = threadIdx.x;
  const int lt = blockIdx.x, h = blockIdx.y, n = blockIdx.z;
  const int r = t >> 2, c = (t & 3) * 16;
  const size_t src = ((size_t)(n * NH + h) * SEQ + lt * 64 + r) * HDIM + c;
  *(short8v*)&Th[r][c]     = *(const short8v*)&VH[src];
  *(short8v*)&Th[r][c + 8] = *(const short8v*)&VH[src + 8];
  *(short8v*)&Tl[r][c]     = *(const short8v*)&VL[src];
  *(short8v*)&Tl[r][c + 8] = *(const short8v*)&VL[src + 8];
  __syncthreads();
  short8v h0, h1, l0, l1;
#pragma unroll
  for (int i = 0; i < 8; ++i) { h0[i] = (short)Th[c + i][r];     l0[i] = (short)Tl[c + i][r]; }
#pragma unroll
  for (int i = 0; i < 8; ++i) { h1[i] = (short)Th[c + 8 + i][r]; l1[i] = (short)Tl[c + 8 + i][r]; }
  const size_t dst = ((size_t)(n * NH + h) * HDIM + r) * SEQ + lt * 64 + c;
  *(short8v*)&TH[dst]     = h0; *(short8v*)&TH[dst + 8] = h1;
  *(short8v*)&TL[dst]     = l0; *(short8v*)&TL[dst + 8] = l1;
}

// ---------------------------------------------------------------------------
// Flash attention, split-bf16 MFMA, XOR-swizzled LDS, bf16 hi/lo output.
// ---------------------------------------------------------------------------
__global__ __launch_bounds__(256)
void attn_mfma_kernel(const ushort_t* __restrict__ qh, const ushort_t* __restrict__ ql,
                      const ushort_t* __restrict__ kh, const ushort_t* __restrict__ kl,
                      const ushort_t* __restrict__ vth, const ushort_t* __restrict__ vtl,
                      ushort_t* __restrict__ abh, ushort_t* __restrict__ abl) {
  __shared__ __align__(16) ushort_t Bh[64][64];
  __shared__ __align__(16) ushort_t Bl[64][64];
  __shared__ __align__(16) float Ps[64][64];

  const int t = threadIdx.x;
  const int lane = t & 63, w = t >> 6;
  const int l15 = lane & 15, l4 = lane >> 4;

  const int bid = blockIdx.x;
  const int xcd = bid & 7, rest = bid >> 3;
  const int qt = rest & 15;
  const int hl = (rest >> 4) * 8 + xcd;
  const int h = hl % NH, n = hl / NH;

  const size_t base = (size_t)(n * NH + h) * (SEQ * HDIM);   // both layouts: 65536/head

  short8v qfh[2], qfl[2];
  {
    const size_t qoff = base + (size_t)(qt * 64 + w * 16 + l15) * HDIM + l4 * 8;
    qfh[0] = *(const short8v*)&qh[qoff];
    qfh[1] = *(const short8v*)&qh[qoff + 32];
    qfl[0] = *(const short8v*)&ql[qoff];
    qfl[1] = *(const short8v*)&ql[qoff + 32];
  }

  f32x4 Oa[4] = {};
  float mrun[4] = {-INFINITY, -INFINITY, -INFINITY, -INFINITY};
  float lrun[4] = {0.f, 0.f, 0.f, 0.f};

  const int sr = t >> 2, scb = (t & 3) * 2;
  const int swz = sr & 7;
  ushort_t* wd0h = &Bh[sr][((scb)     ^ swz) * 8];
  ushort_t* wd1h = &Bh[sr][((scb + 1) ^ swz) * 8];
  ushort_t* wd0l = &Bl[sr][((scb)     ^ swz) * 8];
  ushort_t* wd1l = &Bl[sr][((scb + 1) ^ swz) * 8];

  for (int kt = 0; kt < 16; ++kt) {
    __syncthreads();
    {
      const size_t g = base + (size_t)(kt * 64 + sr) * HDIM + scb * 8;
      *(short8v*)wd0h = *(const short8v*)&kh[g];
      *(short8v*)wd1h = *(const short8v*)&kh[g + 8];
      *(short8v*)wd0l = *(const short8v*)&kl[g];
      *(short8v*)wd1l = *(const short8v*)&kl[g + 8];
    }
    __syncthreads();

    f32x4 S[4] = {};
#pragma unroll
    for (int ks = 0; ks < 2; ++ks)
#pragma unroll
      for (int j = 0; j < 4; ++j) {
        const short8v bh = *(const short8v*)&Bh[l15 + 16 * j][((4 * ks + l4) ^ (l15 & 7)) * 8];
        const short8v bl = *(const short8v*)&Bl[l15 + 16 * j][((4 * ks + l4) ^ (l15 & 7)) * 8];
        S[j] = __builtin_amdgcn_mfma_f32_16x16x32_bf16(qfh[ks], bh, S[j], 0, 0, 0);
        S[j] = __builtin_amdgcn_mfma_f32_16x16x32_bf16(qfl[ks], bh, S[j], 0, 0, 0);
        S[j] = __builtin_amdgcn_mfma_f32_16x16x32_bf16(qfh[ks], bl, S[j], 0, 0, 0);
      }

#pragma unroll
    for (int r = 0; r < 4; ++r) {
      float s0 = S[0][r] * 0.125f, s1 = S[1][r] * 0.125f;
      float s2 = S[2][r] * 0.125f, s3 = S[3][r] * 0.125f;
      float tm = fmaxf(fmaxf(s0, s1), fmaxf(s2, s3));
      for (int off = 1; off < 16; off <<= 1) tm = fmaxf(tm, __shfl_xor(tm, off, 16));
      const float nm  = fmaxf(mrun[r], tm);
      const float scl = __expf(mrun[r] - nm);
      const float p0 = __expf(s0 - nm), p1 = __expf(s1 - nm);
      const float p2 = __expf(s2 - nm), p3 = __expf(s3 - nm);
      float rs = p0 + p1 + p2 + p3;
      for (int off = 1; off < 16; off <<= 1) rs += __shfl_xor(rs, off, 16);
      mrun[r] = nm;
      lrun[r] = lrun[r] * scl + rs;
      Oa[0][r] *= scl; Oa[1][r] *= scl; Oa[2][r] *= scl; Oa[3][r] *= scl;
      const int prow = w * 16 + l4 * 4 + r;
      const int sw = prow & 15;
      Ps[prow][(((l15)      >> 2) ^ sw) * 4 + (l15 & 3)] = p0;
      Ps[prow][(((l15 + 16) >> 2) ^ sw) * 4 + (l15 & 3)] = p1;
      Ps[prow][(((l15 + 32) >> 2) ^ sw) * 4 + (l15 & 3)] = p2;
      Ps[prow][(((l15 + 48) >> 2) ^ sw) * 4 + (l15 & 3)] = p3;
    }

    __syncthreads();
    {
      const size_t g = base + (size_t)sr * SEQ + kt * 64 + scb * 8;
      *(short8v*)wd0h = *(const short8v*)&vth[g];
      *(short8v*)wd1h = *(const short8v*)&vth[g + 8];
      *(short8v*)wd0l = *(const short8v*)&vtl[g];
      *(short8v*)wd1l = *(const short8v*)&vtl[g + 8];
    }
    __syncthreads();

#pragma unroll
    for (int ks = 0; ks < 2; ++ks) {
      float pf[8];
      *(f32x4*)&pf[0] = *(const f32x4*)&Ps[w * 16 + l15][((8 * ks + 2 * l4)     ^ l15) * 4];
      *(f32x4*)&pf[4] = *(const f32x4*)&Ps[w * 16 + l15][((8 * ks + 2 * l4 + 1) ^ l15) * 4];
      short8v ph, pl;
#pragma unroll
      for (int e = 0; e < 8; ++e) {
        ushort_t hh, ll;
        bsplit(pf[e], hh, ll);
        ph[e] = (short)hh; pl[e] = (short)ll;
      }
#pragma unroll
      for (int j = 0; j < 4; ++j) {
        const short8v vh = *(const short8v*)&Bh[l15 + 16 * j][((4 * ks + l4) ^ (l15 & 7)) * 8];
        const short8v vl = *(const short8v*)&Bl[l15 + 16 * j][((4 * ks + l4) ^ (l15 & 7)) * 8];
        Oa[j] = __builtin_amdgcn_mfma_f32_16x16x32_bf16(ph, vh, Oa[j], 0, 0, 0);
        Oa[j] = __builtin_amdgcn_mfma_f32_16x16x32_bf16(pl, vh, Oa[j], 0, 0, 0);
        Oa[j] = __builtin_amdgcn_mfma_f32_16x16x32_bf16(ph, vl, Oa[j], 0, 0, 0);
      }
    }
  }

#pragma unroll
  for (int r = 0; r < 4; ++r) {
    const float inv = 1.0f / lrun[r];
    const int l = qt * 64 + w * 16 + l4 * 4 + r;
    const size_t row = ((size_t)n * SEQ + l) * DMODEL + h * HDIM;
#pragma unroll
    for (int j = 0; j < 4; ++j) {
      ushort_t hh, ll;
      bsplit(Oa[j][r] * inv, hh, ll);
      abh[row + 16 * j + l15] = hh;
      abl[row + 16 * j + l15] = ll;
    }
  }
}

// ---------------------------------------------------------------------------
extern "C" void kernel_launch(void* const* d_in, const int* in_sizes, int n_in,
                              void* d_out, int out_size, void* d_ws, size_t ws_size,
                              hipStream_t stream) {
  (void)in_sizes; (void)n_in; (void)out_size;
  const float* Xq  = (const float*)d_in[0];
  const float* Xkv = (const float*)d_in[1];
  const float* Wq  = (const float*)d_in[2];
  const float* bq  = (const float*)d_in[3];
  const float* Wk  = (const float*)d_in[4];
  const float* bk  = (const float*)d_in[5];
  const float* Wv  = (const float*)d_in[6];
  const float* bv  = (const float*)d_in[7];
  const float* Wo  = (const float*)d_in[8];
  const float* bo  = (const float*)d_in[9];
  float* out = (float*)d_out;

  if (ws_size < 201588736ull) return;
  char* W = (char*)d_ws;
  const size_t HB = 25165824ull;         // one hi or lo buffer: 12.58M ushort
  float*    rope = (float*)W;            // 262,144 B
  // region B (50 MB): X splits, later V^T
  ushort_t* xh  = (ushort_t*)(W + 262144);
  ushort_t* xl  = (ushort_t*)(W + 262144 + HB);
  ushort_t* vth = xh;
  ushort_t* vtl = xl;
  // region C (100 MB): q/k per-head splits, later Wo^T
  char* C0 = W + 262144 + 2 * HB;
  ushort_t* qhi = (ushort_t*)(C0);
  ushort_t* qlo = (ushort_t*)(C0 + HB);
  ushort_t* khi = (ushort_t*)(C0 + 2 * HB);
  ushort_t* klo = (ushort_t*)(C0 + 3 * HB);
  ushort_t* woth = (ushort_t*)(C0);
  ushort_t* wotl = woth + 589824;
  // region D (50 MB): V per-head splits, later attn-out splits
  char* D0 = C0 + 4 * HB;
  ushort_t* vbh = (ushort_t*)(D0);
  ushort_t* vbl = (ushort_t*)(D0 + HB);
  ushort_t* abh = vbh;
  ushort_t* abl = vbl;
  // d_out as scratch for QKV weight transposes (dead before final GEMM writes)
  ushort_t* wqth = (ushort_t*)d_out;            ushort_t* wqtl = wqth + 589824;
  ushort_t* wkth = wqth + 1179648;              ushort_t* wktl = wkth + 589824;
  ushort_t* wvth = wqth + 2359296;              ushort_t* wvtl = wvth + 589824;

  rope_table_kernel<<<64, 256, 0, stream>>>(rope);
  wsplit_t_kernel<<<dim3(12, 12), 256, 0, stream>>>(Wq, wqth, wqtl);
  wsplit_t_kernel<<<dim3(12, 12), 256, 0, stream>>>(Wk, wkth, wktl);
  wsplit_t_kernel<<<dim3(12, 12), 256, 0, stream>>>(Wv, wvth, wvtl);

  const dim3 gg(MTOT / 128, DMODEL / 128);

  split_x_kernel<<<6144, 256, 0, stream>>>(Xq, xh, xl);
  gemm_mfma_kernel<<<gg, 256, 0, stream>>>(xh, xl, wqth, wqtl, bq, nullptr, qhi, qlo, rope, 1);

  split_x_kernel<<<6144, 256, 0, stream>>>(Xkv, xh, xl);
  gemm_mfma_kernel<<<gg, 256, 0, stream>>>(xh, xl, wkth, wktl, bk, nullptr, khi, klo, rope, 1);
  gemm_mfma_kernel<<<gg, 256, 0, stream>>>(xh, xl, wvth, wvtl, bv, nullptr, vbh, vbl, rope, 2);

  vtrans_kernel<<<dim3(16, NH, 16), 256, 0, stream>>>(vbh, vbl, vth, vtl);

  attn_mfma_kernel<<<3072, 256, 0, stream>>>(qhi, qlo, khi, klo, vth, vtl, abh, abl);

  wsplit_t_kernel<<<dim3(12, 12), 256, 0, stream>>>(Wo, woth, wotl);
  gemm_mfma_kernel<<<gg, 256, 0, stream>>>(abh, abl, woth, wotl, bo, out, nullptr, nullptr, rope, 0);
}

// Round 4
// 630.917 us; speedup vs baseline: 2.8296x; 1.0283x over previous
//
#include <hip/hip_runtime.h>
#include <cmath>

#define DMODEL 768
#define SEQ    1024
#define NH     12
#define HDIM   64
#define MTOT   16384   // 16 * 1024

typedef unsigned short ushort_t;
typedef __attribute__((ext_vector_type(8))) short short8v;
typedef __attribute__((ext_vector_type(4))) float f32x4;

// round-to-nearest-even fp32 -> bf16 bits
__device__ __forceinline__ ushort_t bf16rn(float x) {
  unsigned u = __float_as_uint(x);
  return (ushort_t)((u + 0x7FFFu + ((u >> 16) & 1u)) >> 16);
}
__device__ __forceinline__ void bsplit(float x, ushort_t& h, ushort_t& l) {
  h = bf16rn(x);
  float hf = __uint_as_float((unsigned)h << 16);
  l = bf16rn(x - hf);
}

// async global -> LDS, 16 bytes per lane
__device__ __forceinline__ void gld16(const void* g, void* l) {
  __builtin_amdgcn_global_load_lds(
      (const __attribute__((address_space(1))) int*)g,
      (__attribute__((address_space(3))) int*)l, 16, 0, 0);
}

// ---------------------------------------------------------------------------
// RoPE tables (fp64-accurate): [cos_x | sin_x | cos_y | sin_y], each [1024][16]
// ---------------------------------------------------------------------------
__global__ __launch_bounds__(256)
void rope_table_kernel(float* __restrict__ tab) {
  int idx = blockIdx.x * 256 + threadIdx.x;
  if (idx >= SEQ * 16) return;
  int l = idx >> 4, p = idx & 15;
  double u = ((double)(l & 31) + 0.5) / 32.0;
  double v = ((double)(l >> 5) + 0.5) / 32.0;
  double freq = (double)p / (15.0 + 1e-9);
  double inv = pow(10000.0, -freq);
  tab[idx]         = (float)cos(u * inv);
  tab[16384 + idx] = (float)sin(u * inv);
  tab[32768 + idx] = (float)cos(v * inv);
  tab[49152 + idx] = (float)sin(v * inv);
}

// ---------------------------------------------------------------------------
// fp32 -> split bf16 hi/lo, 8 elems/thread
// ---------------------------------------------------------------------------
__global__ __launch_bounds__(256)
void split_x_kernel(const float* __restrict__ X, ushort_t* __restrict__ H,
                    ushort_t* __restrict__ L) {
  const int i = blockIdx.x * 256 + threadIdx.x;
  const float4 a = ((const float4*)X)[i * 2];
  const float4 b = ((const float4*)X)[i * 2 + 1];
  short8v h, l;
  ushort_t hh, ll;
  bsplit(a.x, hh, ll); h[0] = (short)hh; l[0] = (short)ll;
  bsplit(a.y, hh, ll); h[1] = (short)hh; l[1] = (short)ll;
  bsplit(a.z, hh, ll); h[2] = (short)hh; l[2] = (short)ll;
  bsplit(a.w, hh, ll); h[3] = (short)hh; l[3] = (short)ll;
  bsplit(b.x, hh, ll); h[4] = (short)hh; l[4] = (short)ll;
  bsplit(b.y, hh, ll); h[5] = (short)hh; l[5] = (short)ll;
  bsplit(b.z, hh, ll); h[6] = (short)hh; l[6] = (short)ll;
  bsplit(b.w, hh, ll); h[7] = (short)hh; l[7] = (short)ll;
  ((short8v*)H)[i] = h;
  ((short8v*)L)[i] = l;
}

// ---------------------------------------------------------------------------
// W [768k][768n] fp32 -> Wt hi/lo bf16 [768n][768k] (transpose + split)
// ---------------------------------------------------------------------------
__global__ __launch_bounds__(256)
void wsplit_t_kernel(const float* __restrict__ W, ushort_t* __restrict__ TH,
                     ushort_t* __restrict__ TL) {
  __shared__ __align__(16) float T[64][65];
  const int t = threadIdx.x;
  const int kt = blockIdx.x, nt = blockIdx.y;
  const int r = t >> 2, c4 = (t & 3) * 16;
  const float* src = W + (size_t)(kt * 64 + r) * DMODEL + nt * 64 + c4;
#pragma unroll
  for (int i = 0; i < 16; i += 4)
    *(float4*)&T[r][c4 + i] = *(const float4*)&src[i];
  __syncthreads();
  short8v h0, h1, l0, l1;
#pragma unroll
  for (int i = 0; i < 8; ++i) {
    ushort_t hh, ll;
    bsplit(T[c4 + i][r], hh, ll);
    h0[i] = (short)hh; l0[i] = (short)ll;
  }
#pragma unroll
  for (int i = 0; i < 8; ++i) {
    ushort_t hh, ll;
    bsplit(T[c4 + 8 + i][r], hh, ll);
    h1[i] = (short)hh; l1[i] = (short)ll;
  }
  const size_t o = (size_t)(nt * 64 + r) * DMODEL + kt * 64 + c4;
  *(short8v*)&TH[o] = h0; *(short8v*)&TH[o + 8] = h1;
  *(short8v*)&TL[o] = l0; *(short8v*)&TL[o + 8] = l1;
}

// ---------------------------------------------------------------------------
// Split-bf16 MFMA GEMM: C[16384,768] = A @ B + bias (3-term hi/lo).
// mode 0: fp32 C [M][768]. mode 1: +RoPE +oscale, split, per-head [n][h][l][64].
// mode 2: split, per-head (no rope).
// ---------------------------------------------------------------------------
__global__ __launch_bounds__(256)
void gemm_mfma_kernel(const ushort_t* __restrict__ Ahi, const ushort_t* __restrict__ Alo,
                      const ushort_t* __restrict__ Bhi, const ushort_t* __restrict__ Blo,
                      const float* __restrict__ bias, float* __restrict__ Cout,
                      ushort_t* __restrict__ Ohi, ushort_t* __restrict__ Olo,
                      const float* __restrict__ rope, int mode, float oscale) {
  __shared__ __align__(16) ushort_t Ah[128][32];
  __shared__ __align__(16) ushort_t Al[128][32];
  __shared__ __align__(16) ushort_t Bh[128][32];
  __shared__ __align__(16) ushort_t Bl[128][32];

  const int t = threadIdx.x, lane = t & 63, w = t >> 6;
  const int l15 = lane & 15, l4 = lane >> 4;
  const int wm = w >> 1, wn = w & 1;
  const int m0 = blockIdx.x * 128, n0 = blockIdx.y * 128;

  const int crow = t >> 2, ccc = (t & 3) * 8;
  const ushort_t* pAh0 = Ahi + (size_t)(m0 + crow) * DMODEL + ccc;
  const ushort_t* pAh1 = pAh0 + (size_t)64 * DMODEL;
  const ushort_t* pAl0 = Alo + (size_t)(m0 + crow) * DMODEL + ccc;
  const ushort_t* pAl1 = pAl0 + (size_t)64 * DMODEL;
  const ushort_t* pBh0 = Bhi + (size_t)(n0 + crow) * DMODEL + ccc;
  const ushort_t* pBh1 = pBh0 + (size_t)64 * DMODEL;
  const ushort_t* pBl0 = Blo + (size_t)(n0 + crow) * DMODEL + ccc;
  const ushort_t* pBl1 = pBl0 + (size_t)64 * DMODEL;
  void* dAh0 = &Ah[crow][ccc];      void* dAh1 = &Ah[crow + 64][ccc];
  void* dAl0 = &Al[crow][ccc];      void* dAl1 = &Al[crow + 64][ccc];
  void* dBh0 = &Bh[crow][ccc];      void* dBh1 = &Bh[crow + 64][ccc];
  void* dBl0 = &Bl[crow][ccc];      void* dBl1 = &Bl[crow + 64][ccc];

  f32x4 acc[4][4] = {};

  for (int ks = 0; ks < DMODEL / 32; ++ks) {
    __syncthreads();
    gld16(pAh0, dAh0); gld16(pAh1, dAh1);
    gld16(pAl0, dAl0); gld16(pAl1, dAl1);
    gld16(pBh0, dBh0); gld16(pBh1, dBh1);
    gld16(pBl0, dBl0); gld16(pBl1, dBl1);
    pAh0 += 32; pAh1 += 32; pAl0 += 32; pAl1 += 32;
    pBh0 += 32; pBh1 += 32; pBl0 += 32; pBl1 += 32;
    __syncthreads();

    short8v afh[4], afl[4], bfh[4], bfl[4];
#pragma unroll
    for (int f = 0; f < 4; ++f) {
      afh[f] = *(const short8v*)&Ah[wm * 64 + f * 16 + l15][l4 * 8];
      afl[f] = *(const short8v*)&Al[wm * 64 + f * 16 + l15][l4 * 8];
      bfh[f] = *(const short8v*)&Bh[wn * 64 + f * 16 + l15][l4 * 8];
      bfl[f] = *(const short8v*)&Bl[wn * 64 + f * 16 + l15][l4 * 8];
    }
#pragma unroll
    for (int mf = 0; mf < 4; ++mf)
#pragma unroll
      for (int nf = 0; nf < 4; ++nf) {
        acc[mf][nf] = __builtin_amdgcn_mfma_f32_16x16x32_bf16(afh[mf], bfh[nf], acc[mf][nf], 0, 0, 0);
        acc[mf][nf] = __builtin_amdgcn_mfma_f32_16x16x32_bf16(afl[mf], bfh[nf], acc[mf][nf], 0, 0, 0);
        acc[mf][nf] = __builtin_amdgcn_mfma_f32_16x16x32_bf16(afh[mf], bfl[nf], acc[mf][nf], 0, 0, 0);
      }
  }

  float bcol[4];
#pragma unroll
  for (int nf = 0; nf < 4; ++nf) bcol[nf] = bias[n0 + wn * 64 + nf * 16 + l15];

  if (mode == 0) {
#pragma unroll
    for (int mf = 0; mf < 4; ++mf)
#pragma unroll
      for (int r = 0; r < 4; ++r) {
        const int m = m0 + wm * 64 + mf * 16 + l4 * 4 + r;
#pragma unroll
        for (int nf = 0; nf < 4; ++nf)
          Cout[(size_t)m * DMODEL + n0 + wn * 64 + nf * 16 + l15] = acc[mf][nf][r] + bcol[nf];
      }
  } else {
    const int h = blockIdx.y * 2 + wn;
#pragma unroll
    for (int mf = 0; mf < 4; ++mf)
#pragma unroll
      for (int r = 0; r < 4; ++r) {
        const int m = m0 + wm * 64 + mf * 16 + l4 * 4 + r;
        const int l = m & (SEQ - 1);
        const int nb = m >> 10;
        const size_t orow = ((size_t)(nb * NH + h) * SEQ + l) * HDIM;
#pragma unroll
        for (int nf = 0; nf < 4; ++nf) {
          float v = acc[mf][nf][r] + bcol[nf];
          if (mode == 1) {
            const float vp = __shfl_xor(v, 1, 64);
            const int tb = (nf < 2) ? 0 : 32768;
            const int pi = (nf & 1) * 8 + (l15 >> 1);
            const float c = rope[tb + l * 16 + pi];
            const float s = rope[tb + 16384 + l * 16 + pi];
            v = (l15 & 1) ? (vp * s + v * c) : (v * c - vp * s);
            v *= oscale;   // exact pow2 for Q (0.125), 1.0 for K
          }
          ushort_t hh, ll;
          bsplit(v, hh, ll);
          Ohi[orow + nf * 16 + l15] = hh;
          Olo[orow + nf * 16 + l15] = ll;
        }
      }
  }
}

// ---------------------------------------------------------------------------
// V transpose (bf16 hi/lo): [n][h][l][64] -> [n][h][d][1024]
// ---------------------------------------------------------------------------
__global__ __launch_bounds__(256)
void vtrans_kernel(const ushort_t* __restrict__ VH, const ushort_t* __restrict__ VL,
                   ushort_t* __restrict__ TH, ushort_t* __restrict__ TL) {
  __shared__ __align__(16) ushort_t Th[64][72];
  __shared__ __align__(16) ushort_t Tl[64][72];
  const int t = threadIdx.x;
  const int lt = blockIdx.x, h = blockIdx.y, n = blockIdx.z;
  const int r = t >> 2, c = (t & 3) * 16;
  const size_t src = ((size_t)(n * NH + h) * SEQ + lt * 64 + r) * HDIM + c;
  *(short8v*)&Th[r][c]     = *(const short8v*)&VH[src];
  *(short8v*)&Th[r][c + 8] = *(const short8v*)&VH[src + 8];
  *(short8v*)&Tl[r][c]     = *(const short8v*)&VL[src];
  *(short8v*)&Tl[r][c + 8] = *(const short8v*)&VL[src + 8];
  __syncthreads();
  short8v h0, h1, l0, l1;
#pragma unroll
  for (int i = 0; i < 8; ++i) { h0[i] = (short)Th[c + i][r];     l0[i] = (short)Tl[c + i][r]; }
#pragma unroll
  for (int i = 0; i < 8; ++i) { h1[i] = (short)Th[c + 8 + i][r]; l1[i] = (short)Tl[c + 8 + i][r]; }
  const size_t dst = ((size_t)(n * NH + h) * HDIM + r) * SEQ + lt * 64 + c;
  *(short8v*)&TH[dst]     = h0; *(short8v*)&TH[dst + 8] = h1;
  *(short8v*)&TL[dst]     = l0; *(short8v*)&TL[dst + 8] = l1;
}

// ---------------------------------------------------------------------------
// Flash attention, split-bf16 MFMA. Separate K/V LDS (2 barriers/kt),
// reg-prefetch of next tile, defer-max softmax, deferred lrun reduce.
// Q comes pre-scaled by 1/8.
// ---------------------------------------------------------------------------
__global__ __launch_bounds__(256)
void attn_mfma_kernel(const ushort_t* __restrict__ qh, const ushort_t* __restrict__ ql,
                      const ushort_t* __restrict__ kh, const ushort_t* __restrict__ kl,
                      const ushort_t* __restrict__ vth, const ushort_t* __restrict__ vtl,
                      ushort_t* __restrict__ abh, ushort_t* __restrict__ abl) {
  __shared__ __align__(16) ushort_t Kh[64][64];
  __shared__ __align__(16) ushort_t Kl[64][64];
  __shared__ __align__(16) ushort_t Vh[64][64];
  __shared__ __align__(16) ushort_t Vl[64][64];
  __shared__ __align__(16) float Ps[64][64];

  const int t = threadIdx.x;
  const int lane = t & 63, w = t >> 6;
  const int l15 = lane & 15, l4 = lane >> 4;

  const int bid = blockIdx.x;
  const int xcd = bid & 7, rest = bid >> 3;
  const int qt = rest & 15;
  const int hl = (rest >> 4) * 8 + xcd;
  const int h = hl % NH, n = hl / NH;

  const size_t base = (size_t)(n * NH + h) * (SEQ * HDIM);

  short8v qfh[2], qfl[2];
  {
    const size_t qoff = base + (size_t)(qt * 64 + w * 16 + l15) * HDIM + l4 * 8;
    qfh[0] = *(const short8v*)&qh[qoff];
    qfh[1] = *(const short8v*)&qh[qoff + 32];
    qfl[0] = *(const short8v*)&ql[qoff];
    qfl[1] = *(const short8v*)&ql[qoff + 32];
  }

  f32x4 Oa[4] = {};
  float mrun[4] = {-INFINITY, -INFINITY, -INFINITY, -INFINITY};
  float lp[4] = {0.f, 0.f, 0.f, 0.f};

  const int sr = t >> 2, scb = (t & 3) * 2;
  const int swz = sr & 7;

  // prefetch regs for tile kt
  short8v rk0, rk1, rk2, rk3, rv0, rv1, rv2, rv3;
  {
    const size_t gk = base + (size_t)sr * HDIM + scb * 8;
    rk0 = *(const short8v*)&kh[gk];  rk1 = *(const short8v*)&kh[gk + 8];
    rk2 = *(const short8v*)&kl[gk];  rk3 = *(const short8v*)&kl[gk + 8];
    const size_t gv = base + (size_t)sr * SEQ + scb * 8;
    rv0 = *(const short8v*)&vth[gv]; rv1 = *(const short8v*)&vth[gv + 8];
    rv2 = *(const short8v*)&vtl[gv]; rv3 = *(const short8v*)&vtl[gv + 8];
  }

  for (int kt = 0; kt < 16; ++kt) {
    __syncthreads();   // previous-iteration consumers done with K/V LDS
    *(short8v*)&Kh[sr][((scb)     ^ swz) * 8] = rk0;
    *(short8v*)&Kh[sr][((scb + 1) ^ swz) * 8] = rk1;
    *(short8v*)&Kl[sr][((scb)     ^ swz) * 8] = rk2;
    *(short8v*)&Kl[sr][((scb + 1) ^ swz) * 8] = rk3;
    *(short8v*)&Vh[sr][((scb)     ^ swz) * 8] = rv0;
    *(short8v*)&Vh[sr][((scb + 1) ^ swz) * 8] = rv1;
    *(short8v*)&Vl[sr][((scb)     ^ swz) * 8] = rv2;
    *(short8v*)&Vl[sr][((scb + 1) ^ swz) * 8] = rv3;
    __syncthreads();

    if (kt < 15) {   // issue next-tile loads; they drain under this tile's compute
      const size_t gk = base + (size_t)((kt + 1) * 64 + sr) * HDIM + scb * 8;
      rk0 = *(const short8v*)&kh[gk];  rk1 = *(const short8v*)&kh[gk + 8];
      rk2 = *(const short8v*)&kl[gk];  rk3 = *(const short8v*)&kl[gk + 8];
      const size_t gv = base + (size_t)sr * SEQ + (kt + 1) * 64 + scb * 8;
      rv0 = *(const short8v*)&vth[gv]; rv1 = *(const short8v*)&vth[gv + 8];
      rv2 = *(const short8v*)&vtl[gv]; rv3 = *(const short8v*)&vtl[gv + 8];
    }

    // S = Q K^T (3-term split); Q pre-scaled by 1/8
    f32x4 S[4] = {};
    __builtin_amdgcn_s_setprio(1);
#pragma unroll
    for (int ks = 0; ks < 2; ++ks)
#pragma unroll
      for (int j = 0; j < 4; ++j) {
        const short8v bh = *(const short8v*)&Kh[l15 + 16 * j][((4 * ks + l4) ^ (l15 & 7)) * 8];
        const short8v bl = *(const short8v*)&Kl[l15 + 16 * j][((4 * ks + l4) ^ (l15 & 7)) * 8];
        S[j] = __builtin_amdgcn_mfma_f32_16x16x32_bf16(qfh[ks], bh, S[j], 0, 0, 0);
        S[j] = __builtin_amdgcn_mfma_f32_16x16x32_bf16(qfl[ks], bh, S[j], 0, 0, 0);
        S[j] = __builtin_amdgcn_mfma_f32_16x16x32_bf16(qfh[ks], bl, S[j], 0, 0, 0);
      }
    __builtin_amdgcn_s_setprio(0);

    // defer-max online softmax
    float m4[4];
    int ok = 1;
#pragma unroll
    for (int r = 0; r < 4; ++r) {
      m4[r] = fmaxf(fmaxf(S[0][r], S[1][r]), fmaxf(S[2][r], S[3][r]));
      ok &= (m4[r] <= mrun[r] + 8.0f) ? 1 : 0;
    }
    float p0[4], p1[4], p2[4], p3[4];
    if (__all(ok)) {
      // fast path: keep stale max (P bounded by e^8), no rescale, no reductions
#pragma unroll
      for (int r = 0; r < 4; ++r) {
        p0[r] = __expf(S[0][r] - mrun[r]);
        p1[r] = __expf(S[1][r] - mrun[r]);
        p2[r] = __expf(S[2][r] - mrun[r]);
        p3[r] = __expf(S[3][r] - mrun[r]);
        lp[r] += (p0[r] + p1[r]) + (p2[r] + p3[r]);
      }
    } else {
#pragma unroll
      for (int r = 0; r < 4; ++r) {
        float tm = m4[r];
        tm = fmaxf(tm, __shfl_xor(tm, 1, 16));
        tm = fmaxf(tm, __shfl_xor(tm, 2, 16));
        tm = fmaxf(tm, __shfl_xor(tm, 4, 16));
        tm = fmaxf(tm, __shfl_xor(tm, 8, 16));
        const float nm  = fmaxf(mrun[r], tm);
        const float scl = __expf(mrun[r] - nm);
        mrun[r] = nm;
        p0[r] = __expf(S[0][r] - nm);
        p1[r] = __expf(S[1][r] - nm);
        p2[r] = __expf(S[2][r] - nm);
        p3[r] = __expf(S[3][r] - nm);
        lp[r] = lp[r] * scl + ((p0[r] + p1[r]) + (p2[r] + p3[r]));
        Oa[0][r] *= scl; Oa[1][r] *= scl; Oa[2][r] *= scl; Oa[3][r] *= scl;
      }
    }
#pragma unroll
    for (int r = 0; r < 4; ++r) {
      const int prow = w * 16 + l4 * 4 + r;
      const int sw = prow & 15;
      Ps[prow][(((l15)      >> 2) ^ sw) * 4 + (l15 & 3)] = p0[r];
      Ps[prow][(((l15 + 16) >> 2) ^ sw) * 4 + (l15 & 3)] = p1[r];
      Ps[prow][(((l15 + 32) >> 2) ^ sw) * 4 + (l15 & 3)] = p2[r];
      Ps[prow][(((l15 + 48) >> 2) ^ sw) * 4 + (l15 & 3)] = p3[r];
    }
    // Ps stripe is wave-local (rows w*16..w*16+15): no barrier needed

    // O += P V (3-term split)
#pragma unroll
    for (int ks = 0; ks < 2; ++ks) {
      float pf[8];
      *(f32x4*)&pf[0] = *(const f32x4*)&Ps[w * 16 + l15][((8 * ks + 2 * l4)     ^ l15) * 4];
      *(f32x4*)&pf[4] = *(const f32x4*)&Ps[w * 16 + l15][((8 * ks + 2 * l4 + 1) ^ l15) * 4];
      short8v ph, pl;
#pragma unroll
      for (int e = 0; e < 8; ++e) {
        ushort_t hh, ll;
        bsplit(pf[e], hh, ll);
        ph[e] = (short)hh; pl[e] = (short)ll;
      }
      __builtin_amdgcn_s_setprio(1);
#pragma unroll
      for (int j = 0; j < 4; ++j) {
        const short8v vh = *(const short8v*)&Vh[l15 + 16 * j][((4 * ks + l4) ^ (l15 & 7)) * 8];
        const short8v vl = *(const short8v*)&Vl[l15 + 16 * j][((4 * ks + l4) ^ (l15 & 7)) * 8];
        Oa[j] = __builtin_amdgcn_mfma_f32_16x16x32_bf16(ph, vh, Oa[j], 0, 0, 0);
        Oa[j] = __builtin_amdgcn_mfma_f32_16x16x32_bf16(pl, vh, Oa[j], 0, 0, 0);
        Oa[j] = __builtin_amdgcn_mfma_f32_16x16x32_bf16(ph, vl, Oa[j], 0, 0, 0);
      }
      __builtin_amdgcn_s_setprio(0);
    }
  }

  // epilogue: deferred cross-lane lrun reduction, normalize, bf16-split store
#pragma unroll
  for (int r = 0; r < 4; ++r) {
    float s = lp[r];
    s += __shfl_xor(s, 1, 16);
    s += __shfl_xor(s, 2, 16);
    s += __shfl_xor(s, 4, 16);
    s += __shfl_xor(s, 8, 16);
    const float inv = 1.0f / s;
    const int l = qt * 64 + w * 16 + l4 * 4 + r;
    const size_t row = ((size_t)n * SEQ + l) * DMODEL + h * HDIM;
#pragma unroll
    for (int j = 0; j < 4; ++j) {
      ushort_t hh, ll;
      bsplit(Oa[j][r] * inv, hh, ll);
      abh[row + 16 * j + l15] = hh;
      abl[row + 16 * j + l15] = ll;
    }
  }
}

// ---------------------------------------------------------------------------
extern "C" void kernel_launch(void* const* d_in, const int* in_sizes, int n_in,
                              void* d_out, int out_size, void* d_ws, size_t ws_size,
                              hipStream_t stream) {
  (void)in_sizes; (void)n_in; (void)out_size;
  const float* Xq  = (const float*)d_in[0];
  const float* Xkv = (const float*)d_in[1];
  const float* Wq  = (const float*)d_in[2];
  const float* bq  = (const float*)d_in[3];
  const float* Wk  = (const float*)d_in[4];
  const float* bk  = (const float*)d_in[5];
  const float* Wv  = (const float*)d_in[6];
  const float* bv  = (const float*)d_in[7];
  const float* Wo  = (const float*)d_in[8];
  const float* bo  = (const float*)d_in[9];
  float* out = (float*)d_out;

  if (ws_size < 201588736ull) return;
  char* W = (char*)d_ws;
  const size_t HB = 25165824ull;
  float*    rope = (float*)W;
  ushort_t* xh  = (ushort_t*)(W + 262144);
  ushort_t* xl  = (ushort_t*)(W + 262144 + HB);
  ushort_t* vth = xh;
  ushort_t* vtl = xl;
  char* C0 = W + 262144 + 2 * HB;
  ushort_t* qhi = (ushort_t*)(C0);
  ushort_t* qlo = (ushort_t*)(C0 + HB);
  ushort_t* khi = (ushort_t*)(C0 + 2 * HB);
  ushort_t* klo = (ushort_t*)(C0 + 3 * HB);
  ushort_t* woth = (ushort_t*)(C0);
  ushort_t* wotl = woth + 589824;
  char* D0 = C0 + 4 * HB;
  ushort_t* vbh = (ushort_t*)(D0);
  ushort_t* vbl = (ushort_t*)(D0 + HB);
  ushort_t* abh = vbh;
  ushort_t* abl = vbl;
  ushort_t* wqth = (ushort_t*)d_out;            ushort_t* wqtl = wqth + 589824;
  ushort_t* wkth = wqth + 1179648;              ushort_t* wktl = wkth + 589824;
  ushort_t* wvth = wqth + 2359296;              ushort_t* wvtl = wvth + 589824;

  rope_table_kernel<<<64, 256, 0, stream>>>(rope);
  wsplit_t_kernel<<<dim3(12, 12), 256, 0, stream>>>(Wq, wqth, wqtl);
  wsplit_t_kernel<<<dim3(12, 12), 256, 0, stream>>>(Wk, wkth, wktl);
  wsplit_t_kernel<<<dim3(12, 12), 256, 0, stream>>>(Wv, wvth, wvtl);

  const dim3 gg(MTOT / 128, DMODEL / 128);

  split_x_kernel<<<6144, 256, 0, stream>>>(Xq, xh, xl);
  gemm_mfma_kernel<<<gg, 256, 0, stream>>>(xh, xl, wqth, wqtl, bq, nullptr, qhi, qlo, rope, 1, 0.125f);

  split_x_kernel<<<6144, 256, 0, stream>>>(Xkv, xh, xl);
  gemm_mfma_kernel<<<gg, 256, 0, stream>>>(xh, xl, wkth, wktl, bk, nullptr, khi, klo, rope, 1, 1.0f);
  gemm_mfma_kernel<<<gg, 256, 0, stream>>>(xh, xl, wvth, wvtl, bv, nullptr, vbh, vbl, rope, 2, 1.0f);

  vtrans_kernel<<<dim3(16, NH, 16), 256, 0, stream>>>(vbh, vbl, vth, vtl);

  attn_mfma_kernel<<<3072, 256, 0, stream>>>(qhi, qlo, khi, klo, vth, vtl, abh, abl);

  wsplit_t_kernel<<<dim3(12, 12), 256, 0, stream>>>(Wo, woth, wotl);
  gemm_mfma_kernel<<<gg, 256, 0, stream>>>(abh, abl, woth, wotl, bo, out, nullptr, nullptr, rope, 0, 1.0f);
}

// Round 5
// 607.944 us; speedup vs baseline: 2.9365x; 1.0378x over previous
//
#include <hip/hip_runtime.h>
#include <cmath>

#define DMODEL 768
#define SEQ    1024
#define NH     12
#define HDIM   64
#define MTOT   16384   // 16 * 1024

typedef unsigned short ushort_t;
typedef __attribute__((ext_vector_type(8))) short short8v;
typedef __attribute__((ext_vector_type(4))) float f32x4;

union v8u { short8v v; unsigned u[4]; };

// round-to-nearest-even fp32 -> bf16 bits (scalar fallback, used in tiny kernels)
__device__ __forceinline__ ushort_t bf16rn(float x) {
  unsigned u = __float_as_uint(x);
  return (ushort_t)((u + 0x7FFFu + ((u >> 16) & 1u)) >> 16);
}
__device__ __forceinline__ void bsplit(float x, ushort_t& h, ushort_t& l) {
  h = bf16rn(x);
  float hf = __uint_as_float((unsigned)h << 16);
  l = bf16rn(x - hf);
}

// packed 2xf32 -> 2xbf16 (RNE): lo16 = bf16(a), hi16 = bf16(b)
__device__ __forceinline__ unsigned cvt_pk_bf16(float a, float b) {
  unsigned r;
  asm("v_cvt_pk_bf16_f32 %0, %1, %2" : "=v"(r) : "v"(a), "v"(b));
  return r;
}
// split two f32 into packed-bf16 hi-word and lo-word (element0 in lo16)
__device__ __forceinline__ void bsplit2(float x0, float x1, unsigned& hw, unsigned& lw) {
  hw = cvt_pk_bf16(x0, x1);
  const float h0 = __uint_as_float(hw << 16);
  const float h1 = __uint_as_float(hw & 0xFFFF0000u);
  lw = cvt_pk_bf16(x0 - h0, x1 - h1);
}

// async global -> LDS, 16 bytes per lane
__device__ __forceinline__ void gld16(const void* g, void* l) {
  __builtin_amdgcn_global_load_lds(
      (const __attribute__((address_space(1))) int*)g,
      (__attribute__((address_space(3))) int*)l, 16, 0, 0);
}

// ---------------------------------------------------------------------------
// RoPE tables (fp64-accurate): [cos_x | sin_x | cos_y | sin_y], each [1024][16]
// ---------------------------------------------------------------------------
__global__ __launch_bounds__(256)
void rope_table_kernel(float* __restrict__ tab) {
  int idx = blockIdx.x * 256 + threadIdx.x;
  if (idx >= SEQ * 16) return;
  int l = idx >> 4, p = idx & 15;
  double u = ((double)(l & 31) + 0.5) / 32.0;
  double v = ((double)(l >> 5) + 0.5) / 32.0;
  double freq = (double)p / (15.0 + 1e-9);
  double inv = pow(10000.0, -freq);
  tab[idx]         = (float)cos(u * inv);
  tab[16384 + idx] = (float)sin(u * inv);
  tab[32768 + idx] = (float)cos(v * inv);
  tab[49152 + idx] = (float)sin(v * inv);
}

// ---------------------------------------------------------------------------
// fp32 -> split bf16 hi/lo, 8 elems/thread
// ---------------------------------------------------------------------------
__global__ __launch_bounds__(256)
void split_x_kernel(const float* __restrict__ X, ushort_t* __restrict__ H,
                    ushort_t* __restrict__ L) {
  const int i = blockIdx.x * 256 + threadIdx.x;
  const float4 a = ((const float4*)X)[i * 2];
  const float4 b = ((const float4*)X)[i * 2 + 1];
  v8u h, l;
  bsplit2(a.x, a.y, h.u[0], l.u[0]);
  bsplit2(a.z, a.w, h.u[1], l.u[1]);
  bsplit2(b.x, b.y, h.u[2], l.u[2]);
  bsplit2(b.z, b.w, h.u[3], l.u[3]);
  ((short8v*)H)[i] = h.v;
  ((short8v*)L)[i] = l.v;
}

// ---------------------------------------------------------------------------
// W [768k][768n] fp32 -> Wt hi/lo bf16 [768n][768k] (transpose + split)
// ---------------------------------------------------------------------------
__global__ __launch_bounds__(256)
void wsplit_t_kernel(const float* __restrict__ W, ushort_t* __restrict__ TH,
                     ushort_t* __restrict__ TL) {
  __shared__ __align__(16) float T[64][65];
  const int t = threadIdx.x;
  const int kt = blockIdx.x, nt = blockIdx.y;
  const int r = t >> 2, c4 = (t & 3) * 16;
  const float* src = W + (size_t)(kt * 64 + r) * DMODEL + nt * 64 + c4;
#pragma unroll
  for (int i = 0; i < 16; i += 4)
    *(float4*)&T[r][c4 + i] = *(const float4*)&src[i];
  __syncthreads();
  short8v h0, h1, l0, l1;
#pragma unroll
  for (int i = 0; i < 8; ++i) {
    ushort_t hh, ll;
    bsplit(T[c4 + i][r], hh, ll);
    h0[i] = (short)hh; l0[i] = (short)ll;
  }
#pragma unroll
  for (int i = 0; i < 8; ++i) {
    ushort_t hh, ll;
    bsplit(T[c4 + 8 + i][r], hh, ll);
    h1[i] = (short)hh; l1[i] = (short)ll;
  }
  const size_t o = (size_t)(nt * 64 + r) * DMODEL + kt * 64 + c4;
  *(short8v*)&TH[o] = h0; *(short8v*)&TH[o + 8] = h1;
  *(short8v*)&TL[o] = l0; *(short8v*)&TL[o + 8] = l1;
}

// ---------------------------------------------------------------------------
// Split-bf16 MFMA GEMM: C[16384,768] = A @ B + bias (3-term hi/lo).
// mode 0: fp32 C [M][768]. mode 1: +RoPE +oscale, split, per-head [n][h][l][64].
// mode 2: split, per-head (no rope).
// ---------------------------------------------------------------------------
__global__ __launch_bounds__(256)
void gemm_mfma_kernel(const ushort_t* __restrict__ Ahi, const ushort_t* __restrict__ Alo,
                      const ushort_t* __restrict__ Bhi, const ushort_t* __restrict__ Blo,
                      const float* __restrict__ bias, float* __restrict__ Cout,
                      ushort_t* __restrict__ Ohi, ushort_t* __restrict__ Olo,
                      const float* __restrict__ rope, int mode, float oscale) {
  __shared__ __align__(16) ushort_t Ah[128][32];
  __shared__ __align__(16) ushort_t Al[128][32];
  __shared__ __align__(16) ushort_t Bh[128][32];
  __shared__ __align__(16) ushort_t Bl[128][32];

  const int t = threadIdx.x, lane = t & 63, w = t >> 6;
  const int l15 = lane & 15, l4 = lane >> 4;
  const int wm = w >> 1, wn = w & 1;
  const int m0 = blockIdx.x * 128, n0 = blockIdx.y * 128;

  const int crow = t >> 2, ccc = (t & 3) * 8;
  const ushort_t* pAh0 = Ahi + (size_t)(m0 + crow) * DMODEL + ccc;
  const ushort_t* pAh1 = pAh0 + (size_t)64 * DMODEL;
  const ushort_t* pAl0 = Alo + (size_t)(m0 + crow) * DMODEL + ccc;
  const ushort_t* pAl1 = pAl0 + (size_t)64 * DMODEL;
  const ushort_t* pBh0 = Bhi + (size_t)(n0 + crow) * DMODEL + ccc;
  const ushort_t* pBh1 = pBh0 + (size_t)64 * DMODEL;
  const ushort_t* pBl0 = Blo + (size_t)(n0 + crow) * DMODEL + ccc;
  const ushort_t* pBl1 = pBl0 + (size_t)64 * DMODEL;
  void* dAh0 = &Ah[crow][ccc];      void* dAh1 = &Ah[crow + 64][ccc];
  void* dAl0 = &Al[crow][ccc];      void* dAl1 = &Al[crow + 64][ccc];
  void* dBh0 = &Bh[crow][ccc];      void* dBh1 = &Bh[crow + 64][ccc];
  void* dBl0 = &Bl[crow][ccc];      void* dBl1 = &Bl[crow + 64][ccc];

  f32x4 acc[4][4] = {};

  for (int ks = 0; ks < DMODEL / 32; ++ks) {
    __syncthreads();
    gld16(pAh0, dAh0); gld16(pAh1, dAh1);
    gld16(pAl0, dAl0); gld16(pAl1, dAl1);
    gld16(pBh0, dBh0); gld16(pBh1, dBh1);
    gld16(pBl0, dBl0); gld16(pBl1, dBl1);
    pAh0 += 32; pAh1 += 32; pAl0 += 32; pAl1 += 32;
    pBh0 += 32; pBh1 += 32; pBl0 += 32; pBl1 += 32;
    __syncthreads();

    short8v afh[4], afl[4], bfh[4], bfl[4];
#pragma unroll
    for (int f = 0; f < 4; ++f) {
      afh[f] = *(const short8v*)&Ah[wm * 64 + f * 16 + l15][l4 * 8];
      afl[f] = *(const short8v*)&Al[wm * 64 + f * 16 + l15][l4 * 8];
      bfh[f] = *(const short8v*)&Bh[wn * 64 + f * 16 + l15][l4 * 8];
      bfl[f] = *(const short8v*)&Bl[wn * 64 + f * 16 + l15][l4 * 8];
    }
#pragma unroll
    for (int mf = 0; mf < 4; ++mf)
#pragma unroll
      for (int nf = 0; nf < 4; ++nf) {
        acc[mf][nf] = __builtin_amdgcn_mfma_f32_16x16x32_bf16(afh[mf], bfh[nf], acc[mf][nf], 0, 0, 0);
        acc[mf][nf] = __builtin_amdgcn_mfma_f32_16x16x32_bf16(afl[mf], bfh[nf], acc[mf][nf], 0, 0, 0);
        acc[mf][nf] = __builtin_amdgcn_mfma_f32_16x16x32_bf16(afh[mf], bfl[nf], acc[mf][nf], 0, 0, 0);
      }
  }

  float bcol[4];
#pragma unroll
  for (int nf = 0; nf < 4; ++nf) bcol[nf] = bias[n0 + wn * 64 + nf * 16 + l15];

  if (mode == 0) {
#pragma unroll
    for (int mf = 0; mf < 4; ++mf)
#pragma unroll
      for (int r = 0; r < 4; ++r) {
        const int m = m0 + wm * 64 + mf * 16 + l4 * 4 + r;
#pragma unroll
        for (int nf = 0; nf < 4; ++nf)
          Cout[(size_t)m * DMODEL + n0 + wn * 64 + nf * 16 + l15] = acc[mf][nf][r] + bcol[nf];
      }
  } else {
    const int h = blockIdx.y * 2 + wn;
#pragma unroll
    for (int mf = 0; mf < 4; ++mf)
#pragma unroll
      for (int r = 0; r < 4; ++r) {
        const int m = m0 + wm * 64 + mf * 16 + l4 * 4 + r;
        const int l = m & (SEQ - 1);
        const int nb = m >> 10;
        const size_t orow = ((size_t)(nb * NH + h) * SEQ + l) * HDIM;
        float vv[4];
#pragma unroll
        for (int nf = 0; nf < 4; ++nf) {
          float v = acc[mf][nf][r] + bcol[nf];
          if (mode == 1) {
            const float vp = __shfl_xor(v, 1, 64);
            const int tb = (nf < 2) ? 0 : 32768;
            const int pi = (nf & 1) * 8 + (l15 >> 1);
            const float c = rope[tb + l * 16 + pi];
            const float s = rope[tb + 16384 + l * 16 + pi];
            v = (l15 & 1) ? (vp * s + v * c) : (v * c - vp * s);
            v *= oscale;   // Q: log2e/8 (exp2-domain); K: 1.0
          }
          vv[nf] = v;
        }
        unsigned h01, l01, h23, l23;
        bsplit2(vv[0], vv[1], h01, l01);
        bsplit2(vv[2], vv[3], h23, l23);
        Ohi[orow + 0 * 16 + l15] = (ushort_t)(h01 & 0xFFFFu);
        Ohi[orow + 1 * 16 + l15] = (ushort_t)(h01 >> 16);
        Ohi[orow + 2 * 16 + l15] = (ushort_t)(h23 & 0xFFFFu);
        Ohi[orow + 3 * 16 + l15] = (ushort_t)(h23 >> 16);
        Olo[orow + 0 * 16 + l15] = (ushort_t)(l01 & 0xFFFFu);
        Olo[orow + 1 * 16 + l15] = (ushort_t)(l01 >> 16);
        Olo[orow + 2 * 16 + l15] = (ushort_t)(l23 & 0xFFFFu);
        Olo[orow + 3 * 16 + l15] = (ushort_t)(l23 >> 16);
      }
  }
}

// ---------------------------------------------------------------------------
// V transpose (bf16 hi/lo): [n][h][l][64] -> [n][h][d][1024]
// ---------------------------------------------------------------------------
__global__ __launch_bounds__(256)
void vtrans_kernel(const ushort_t* __restrict__ VH, const ushort_t* __restrict__ VL,
                   ushort_t* __restrict__ TH, ushort_t* __restrict__ TL) {
  __shared__ __align__(16) ushort_t Th[64][72];
  __shared__ __align__(16) ushort_t Tl[64][72];
  const int t = threadIdx.x;
  const int lt = blockIdx.x, h = blockIdx.y, n = blockIdx.z;
  const int r = t >> 2, c = (t & 3) * 16;
  const size_t src = ((size_t)(n * NH + h) * SEQ + lt * 64 + r) * HDIM + c;
  *(short8v*)&Th[r][c]     = *(const short8v*)&VH[src];
  *(short8v*)&Th[r][c + 8] = *(const short8v*)&VH[src + 8];
  *(short8v*)&Tl[r][c]     = *(const short8v*)&VL[src];
  *(short8v*)&Tl[r][c + 8] = *(const short8v*)&VL[src + 8];
  __syncthreads();
  short8v h0, h1, l0, l1;
#pragma unroll
  for (int i = 0; i < 8; ++i) { h0[i] = (short)Th[c + i][r];     l0[i] = (short)Tl[c + i][r]; }
#pragma unroll
  for (int i = 0; i < 8; ++i) { h1[i] = (short)Th[c + 8 + i][r]; l1[i] = (short)Tl[c + 8 + i][r]; }
  const size_t dst = ((size_t)(n * NH + h) * HDIM + r) * SEQ + lt * 64 + c;
  *(short8v*)&TH[dst]     = h0; *(short8v*)&TH[dst + 8] = h1;
  *(short8v*)&TL[dst]     = l0; *(short8v*)&TL[dst + 8] = l1;
}

// ---------------------------------------------------------------------------
// Flash attention, split-bf16 MFMA, exp2-domain softmax (Q pre-scaled by
// log2e/8). Separate K/V LDS, reg-prefetch, defer-max, deferred lrun reduce,
// cvt_pk-based P split.
// ---------------------------------------------------------------------------
__global__ __launch_bounds__(256)
void attn_mfma_kernel(const ushort_t* __restrict__ qh, const ushort_t* __restrict__ ql,
                      const ushort_t* __restrict__ kh, const ushort_t* __restrict__ kl,
                      const ushort_t* __restrict__ vth, const ushort_t* __restrict__ vtl,
                      ushort_t* __restrict__ abh, ushort_t* __restrict__ abl) {
  __shared__ __align__(16) ushort_t Kh[64][64];
  __shared__ __align__(16) ushort_t Kl[64][64];
  __shared__ __align__(16) ushort_t Vh[64][64];
  __shared__ __align__(16) ushort_t Vl[64][64];
  __shared__ __align__(16) float Ps[64][64];

  const int t = threadIdx.x;
  const int lane = t & 63, w = t >> 6;
  const int l15 = lane & 15, l4 = lane >> 4;

  const int bid = blockIdx.x;
  const int xcd = bid & 7, rest = bid >> 3;
  const int qt = rest & 15;
  const int hl = (rest >> 4) * 8 + xcd;
  const int h = hl % NH, n = hl / NH;

  const size_t base = (size_t)(n * NH + h) * (SEQ * HDIM);

  short8v qfh[2], qfl[2];
  {
    const size_t qoff = base + (size_t)(qt * 64 + w * 16 + l15) * HDIM + l4 * 8;
    qfh[0] = *(const short8v*)&qh[qoff];
    qfh[1] = *(const short8v*)&qh[qoff + 32];
    qfl[0] = *(const short8v*)&ql[qoff];
    qfl[1] = *(const short8v*)&ql[qoff + 32];
  }

  f32x4 Oa[4] = {};
  float mrun[4] = {-INFINITY, -INFINITY, -INFINITY, -INFINITY};
  float lp[4] = {0.f, 0.f, 0.f, 0.f};

  const int sr = t >> 2, scb = (t & 3) * 2;
  const int swz = sr & 7;

  short8v rk0, rk1, rk2, rk3, rv0, rv1, rv2, rv3;
  {
    const size_t gk = base + (size_t)sr * HDIM + scb * 8;
    rk0 = *(const short8v*)&kh[gk];  rk1 = *(const short8v*)&kh[gk + 8];
    rk2 = *(const short8v*)&kl[gk];  rk3 = *(const short8v*)&kl[gk + 8];
    const size_t gv = base + (size_t)sr * SEQ + scb * 8;
    rv0 = *(const short8v*)&vth[gv]; rv1 = *(const short8v*)&vth[gv + 8];
    rv2 = *(const short8v*)&vtl[gv]; rv3 = *(const short8v*)&vtl[gv + 8];
  }

  for (int kt = 0; kt < 16; ++kt) {
    __syncthreads();
    *(short8v*)&Kh[sr][((scb)     ^ swz) * 8] = rk0;
    *(short8v*)&Kh[sr][((scb + 1) ^ swz) * 8] = rk1;
    *(short8v*)&Kl[sr][((scb)     ^ swz) * 8] = rk2;
    *(short8v*)&Kl[sr][((scb + 1) ^ swz) * 8] = rk3;
    *(short8v*)&Vh[sr][((scb)     ^ swz) * 8] = rv0;
    *(short8v*)&Vh[sr][((scb + 1) ^ swz) * 8] = rv1;
    *(short8v*)&Vl[sr][((scb)     ^ swz) * 8] = rv2;
    *(short8v*)&Vl[sr][((scb + 1) ^ swz) * 8] = rv3;
    __syncthreads();

    if (kt < 15) {
      const size_t gk = base + (size_t)((kt + 1) * 64 + sr) * HDIM + scb * 8;
      rk0 = *(const short8v*)&kh[gk];  rk1 = *(const short8v*)&kh[gk + 8];
      rk2 = *(const short8v*)&kl[gk];  rk3 = *(const short8v*)&kl[gk + 8];
      const size_t gv = base + (size_t)sr * SEQ + (kt + 1) * 64 + scb * 8;
      rv0 = *(const short8v*)&vth[gv]; rv1 = *(const short8v*)&vth[gv + 8];
      rv2 = *(const short8v*)&vtl[gv]; rv3 = *(const short8v*)&vtl[gv + 8];
    }

    // S = Q K^T (3-term split); S is in log2 domain (Q pre-scaled by log2e/8)
    f32x4 S[4] = {};
    __builtin_amdgcn_s_setprio(1);
#pragma unroll
    for (int ks = 0; ks < 2; ++ks)
#pragma unroll
      for (int j = 0; j < 4; ++j) {
        const short8v bh = *(const short8v*)&Kh[l15 + 16 * j][((4 * ks + l4) ^ (l15 & 7)) * 8];
        const short8v bl = *(const short8v*)&Kl[l15 + 16 * j][((4 * ks + l4) ^ (l15 & 7)) * 8];
        S[j] = __builtin_amdgcn_mfma_f32_16x16x32_bf16(qfh[ks], bh, S[j], 0, 0, 0);
        S[j] = __builtin_amdgcn_mfma_f32_16x16x32_bf16(qfl[ks], bh, S[j], 0, 0, 0);
        S[j] = __builtin_amdgcn_mfma_f32_16x16x32_bf16(qfh[ks], bl, S[j], 0, 0, 0);
      }
    __builtin_amdgcn_s_setprio(0);

    // defer-max online softmax (log2 domain; 11.5 = 8*log2e)
    float m4[4];
    int ok = 1;
#pragma unroll
    for (int r = 0; r < 4; ++r) {
      m4[r] = fmaxf(fmaxf(S[0][r], S[1][r]), fmaxf(S[2][r], S[3][r]));
      ok &= (m4[r] <= mrun[r] + 11.5f) ? 1 : 0;
    }
    float p0[4], p1[4], p2[4], p3[4];
    if (__all(ok)) {
#pragma unroll
      for (int r = 0; r < 4; ++r) {
        p0[r] = __builtin_amdgcn_exp2f(S[0][r] - mrun[r]);
        p1[r] = __builtin_amdgcn_exp2f(S[1][r] - mrun[r]);
        p2[r] = __builtin_amdgcn_exp2f(S[2][r] - mrun[r]);
        p3[r] = __builtin_amdgcn_exp2f(S[3][r] - mrun[r]);
        lp[r] += (p0[r] + p1[r]) + (p2[r] + p3[r]);
      }
    } else {
#pragma unroll
      for (int r = 0; r < 4; ++r) {
        float tm = m4[r];
        tm = fmaxf(tm, __shfl_xor(tm, 1, 16));
        tm = fmaxf(tm, __shfl_xor(tm, 2, 16));
        tm = fmaxf(tm, __shfl_xor(tm, 4, 16));
        tm = fmaxf(tm, __shfl_xor(tm, 8, 16));
        const float nm  = fmaxf(mrun[r], tm);
        const float scl = __builtin_amdgcn_exp2f(mrun[r] - nm);
        mrun[r] = nm;
        p0[r] = __builtin_amdgcn_exp2f(S[0][r] - nm);
        p1[r] = __builtin_amdgcn_exp2f(S[1][r] - nm);
        p2[r] = __builtin_amdgcn_exp2f(S[2][r] - nm);
        p3[r] = __builtin_amdgcn_exp2f(S[3][r] - nm);
        lp[r] = lp[r] * scl + ((p0[r] + p1[r]) + (p2[r] + p3[r]));
        Oa[0][r] *= scl; Oa[1][r] *= scl; Oa[2][r] *= scl; Oa[3][r] *= scl;
      }
    }
#pragma unroll
    for (int r = 0; r < 4; ++r) {
      const int prow = w * 16 + l4 * 4 + r;
      const int sw = prow & 15;
      Ps[prow][(((l15)      >> 2) ^ sw) * 4 + (l15 & 3)] = p0[r];
      Ps[prow][(((l15 + 16) >> 2) ^ sw) * 4 + (l15 & 3)] = p1[r];
      Ps[prow][(((l15 + 32) >> 2) ^ sw) * 4 + (l15 & 3)] = p2[r];
      Ps[prow][(((l15 + 48) >> 2) ^ sw) * 4 + (l15 & 3)] = p3[r];
    }
    // Ps stripe is wave-local (rows w*16..w*16+15): no barrier needed

    // O += P V (3-term split), cvt_pk-based P split
#pragma unroll
    for (int ks = 0; ks < 2; ++ks) {
      float pf[8];
      *(f32x4*)&pf[0] = *(const f32x4*)&Ps[w * 16 + l15][((8 * ks + 2 * l4)     ^ l15) * 4];
      *(f32x4*)&pf[4] = *(const f32x4*)&Ps[w * 16 + l15][((8 * ks + 2 * l4 + 1) ^ l15) * 4];
      v8u ph, pl;
      bsplit2(pf[0], pf[1], ph.u[0], pl.u[0]);
      bsplit2(pf[2], pf[3], ph.u[1], pl.u[1]);
      bsplit2(pf[4], pf[5], ph.u[2], pl.u[2]);
      bsplit2(pf[6], pf[7], ph.u[3], pl.u[3]);
      __builtin_amdgcn_s_setprio(1);
#pragma unroll
      for (int j = 0; j < 4; ++j) {
        const short8v vh = *(const short8v*)&Vh[l15 + 16 * j][((4 * ks + l4) ^ (l15 & 7)) * 8];
        const short8v vl = *(const short8v*)&Vl[l15 + 16 * j][((4 * ks + l4) ^ (l15 & 7)) * 8];
        Oa[j] = __builtin_amdgcn_mfma_f32_16x16x32_bf16(ph.v, vh, Oa[j], 0, 0, 0);
        Oa[j] = __builtin_amdgcn_mfma_f32_16x16x32_bf16(pl.v, vh, Oa[j], 0, 0, 0);
        Oa[j] = __builtin_amdgcn_mfma_f32_16x16x32_bf16(ph.v, vl, Oa[j], 0, 0, 0);
      }
      __builtin_amdgcn_s_setprio(0);
    }
  }

  // epilogue: deferred cross-lane lrun reduction, normalize, bf16-split store
#pragma unroll
  for (int r = 0; r < 4; ++r) {
    float s = lp[r];
    s += __shfl_xor(s, 1, 16);
    s += __shfl_xor(s, 2, 16);
    s += __shfl_xor(s, 4, 16);
    s += __shfl_xor(s, 8, 16);
    const float inv = 1.0f / s;
    const int l = qt * 64 + w * 16 + l4 * 4 + r;
    const size_t row = ((size_t)n * SEQ + l) * DMODEL + h * HDIM;
    const float o0 = Oa[0][r] * inv, o1 = Oa[1][r] * inv;
    const float o2 = Oa[2][r] * inv, o3 = Oa[3][r] * inv;
    unsigned h01, l01, h23, l23;
    bsplit2(o0, o1, h01, l01);
    bsplit2(o2, o3, h23, l23);
    abh[row + 0 * 16 + l15] = (ushort_t)(h01 & 0xFFFFu);
    abh[row + 1 * 16 + l15] = (ushort_t)(h01 >> 16);
    abh[row + 2 * 16 + l15] = (ushort_t)(h23 & 0xFFFFu);
    abh[row + 3 * 16 + l15] = (ushort_t)(h23 >> 16);
    abl[row + 0 * 16 + l15] = (ushort_t)(l01 & 0xFFFFu);
    abl[row + 1 * 16 + l15] = (ushort_t)(l01 >> 16);
    abl[row + 2 * 16 + l15] = (ushort_t)(l23 & 0xFFFFu);
    abl[row + 3 * 16 + l15] = (ushort_t)(l23 >> 16);
  }
}

// ---------------------------------------------------------------------------
extern "C" void kernel_launch(void* const* d_in, const int* in_sizes, int n_in,
                              void* d_out, int out_size, void* d_ws, size_t ws_size,
                              hipStream_t stream) {
  (void)in_sizes; (void)n_in; (void)out_size;
  const float* Xq  = (const float*)d_in[0];
  const float* Xkv = (const float*)d_in[1];
  const float* Wq  = (const float*)d_in[2];
  const float* bq  = (const float*)d_in[3];
  const float* Wk  = (const float*)d_in[4];
  const float* bk  = (const float*)d_in[5];
  const float* Wv  = (const float*)d_in[6];
  const float* bv  = (const float*)d_in[7];
  const float* Wo  = (const float*)d_in[8];
  const float* bo  = (const float*)d_in[9];
  float* out = (float*)d_out;

  if (ws_size < 201588736ull) return;
  char* W = (char*)d_ws;
  const size_t HB = 25165824ull;
  float*    rope = (float*)W;
  ushort_t* xh  = (ushort_t*)(W + 262144);
  ushort_t* xl  = (ushort_t*)(W + 262144 + HB);
  ushort_t* vth = xh;
  ushort_t* vtl = xl;
  char* C0 = W + 262144 + 2 * HB;
  ushort_t* qhi = (ushort_t*)(C0);
  ushort_t* qlo = (ushort_t*)(C0 + HB);
  ushort_t* khi = (ushort_t*)(C0 + 2 * HB);
  ushort_t* klo = (ushort_t*)(C0 + 3 * HB);
  ushort_t* woth = (ushort_t*)(C0);
  ushort_t* wotl = woth + 589824;
  char* D0 = C0 + 4 * HB;
  ushort_t* vbh = (ushort_t*)(D0);
  ushort_t* vbl = (ushort_t*)(D0 + HB);
  ushort_t* abh = vbh;
  ushort_t* abl = vbl;
  ushort_t* wqth = (ushort_t*)d_out;            ushort_t* wqtl = wqth + 589824;
  ushort_t* wkth = wqth + 1179648;              ushort_t* wktl = wkth + 589824;
  ushort_t* wvth = wqth + 2359296;              ushort_t* wvtl = wvth + 589824;

  rope_table_kernel<<<64, 256, 0, stream>>>(rope);
  wsplit_t_kernel<<<dim3(12, 12), 256, 0, stream>>>(Wq, wqth, wqtl);
  wsplit_t_kernel<<<dim3(12, 12), 256, 0, stream>>>(Wk, wkth, wktl);
  wsplit_t_kernel<<<dim3(12, 12), 256, 0, stream>>>(Wv, wvth, wvtl);

  const dim3 gg(MTOT / 128, DMODEL / 128);
  const float q_scale = 0.125f * 1.44269504088896340736f;   // (1/8)*log2(e)

  split_x_kernel<<<6144, 256, 0, stream>>>(Xq, xh, xl);
  gemm_mfma_kernel<<<gg, 256, 0, stream>>>(xh, xl, wqth, wqtl, bq, nullptr, qhi, qlo, rope, 1, q_scale);

  split_x_kernel<<<6144, 256, 0, stream>>>(Xkv, xh, xl);
  gemm_mfma_kernel<<<gg, 256, 0, stream>>>(xh, xl, wkth, wktl, bk, nullptr, khi, klo, rope, 1, 1.0f);
  gemm_mfma_kernel<<<gg, 256, 0, stream>>>(xh, xl, wvth, wvtl, bv, nullptr, vbh, vbl, rope, 2, 1.0f);

  vtrans_kernel<<<dim3(16, NH, 16), 256, 0, stream>>>(vbh, vbl, vth, vtl);

  attn_mfma_kernel<<<3072, 256, 0, stream>>>(qhi, qlo, khi, klo, vth, vtl, abh, abl);

  wsplit_t_kernel<<<dim3(12, 12), 256, 0, stream>>>(Wo, woth, wotl);
  gemm_mfma_kernel<<<gg, 256, 0, stream>>>(abh, abl, woth, wotl, bo, out, nullptr, nullptr, rope, 0, 1.0f);
}